// Round 1
// baseline (1557.874 us; speedup 1.0000x reference)
//
#include <hip/hip_runtime.h>
#include <hip/hip_bf16.h>

#define BSZ 2
#define NADJ 2
#define NN 2048
#define DE 64
#define HH 8
#define F1 64
#define NF 192   // 3*DE
#define K1 512   // HH*F1

// ---------------- build feat = [emb0[v], emb1[v], local_emb] ----------------
__global__ __launch_bounds__(256) void k_build_feat(
    const int* __restrict__ vert, const float* __restrict__ lemb,
    const float* __restrict__ emb0, const float* __restrict__ emb1,
    float* __restrict__ feat) {
  int idx = blockIdx.x * 256 + threadIdx.x;          // over BSZ*NN*NF
  int f = idx % NF;
  int bn = idx / NF;
  int v = vert[bn];
  float val;
  if (f < 64)       val = emb0[v * 64 + f];
  else if (f < 128) val = emb1[v * 64 + (f - 64)];
  else              val = lemb[bn * 64 + (f - 128)];
  feat[idx] = val;
}

// ---------------- per-head GEMM: out[b,h,n,o] = sum_k in[b,n,k]*w[h,k,o] ----
template <int K>
__global__ __launch_bounds__(256) void k_gemm(
    const float* __restrict__ in, const float* __restrict__ w,
    float* __restrict__ outp, int nheads) {
  __shared__ float a_lds[64][68];   // padded; fp32 staging via float4
  __shared__ float w_lds[64][64];
  int tile = blockIdx.x, h = blockIdx.y, b = blockIdx.z;
  int t = threadIdx.x;
  int row0 = tile * 64;
  int c4 = (t & 15) * 4, r4 = (t >> 4) * 4;
  float acc[16] = {};
  const float* inb = in + (size_t)b * NN * K + (size_t)row0 * K;
  const float* wb  = w + (size_t)h * K * 64;
  for (int k0 = 0; k0 < K; k0 += 64) {
    __syncthreads();
#pragma unroll
    for (int q = 0; q < 4; ++q) {
      int idx = (t + 256 * q) * 4;
      int rr = idx >> 6, kk = idx & 63;
      *(float4*)&a_lds[rr][kk] = *(const float4*)&inb[(size_t)rr * K + k0 + kk];
      *(float4*)&w_lds[rr][kk] = *(const float4*)&wb[(size_t)(k0 + rr) * 64 + kk];
    }
    __syncthreads();
#pragma unroll 4
    for (int kk = 0; kk < 64; ++kk) {
      float4 wv = *(const float4*)&w_lds[kk][c4];
#pragma unroll
      for (int rr = 0; rr < 4; ++rr) {
        float av = a_lds[r4 + rr][kk];
        acc[rr * 4 + 0] += av * wv.x;
        acc[rr * 4 + 1] += av * wv.y;
        acc[rr * 4 + 2] += av * wv.z;
        acc[rr * 4 + 3] += av * wv.w;
      }
    }
  }
  size_t ob = (((size_t)b * nheads + h) * NN + row0 + r4) * 64 + c4;
#pragma unroll
  for (int rr = 0; rr < 4; ++rr) {
    float4 o = {acc[rr * 4 + 0], acc[rr * 4 + 1], acc[rr * 4 + 2], acc[rr * 4 + 3]};
    *(float4*)&outp[ob + (size_t)rr * 64] = o;
  }
}

// ---------------- s,d vectors: s[b,n,h] = sum_o tanh(hp[b,h,n,o])*a_src[h,o] -
__global__ __launch_bounds__(256) void k_sd(
    const float* __restrict__ hp, const float* __restrict__ a_src,
    const float* __restrict__ a_dst, float* __restrict__ sT, float* __restrict__ dT) {
  int gw = blockIdx.x * 4 + (threadIdx.x >> 6);   // over BSZ*HH*NN (b,h,n)
  int lane = threadIdx.x & 63;
  int n = gw & (NN - 1);
  int bh = gw >> 11;
  int h = bh & (HH - 1);
  int b = bh >> 3;
  float v = tanhf(hp[(size_t)gw * 64 + lane]);
  float sv = v * a_src[h * 64 + lane];
  float dv = v * a_dst[h * 64 + lane];
  for (int off = 32; off; off >>= 1) {
    sv += __shfl_down(sv, off);
    dv += __shfl_down(dv, off);
  }
  if (lane == 0) {
    sT[((size_t)b * NN + n) * HH + h] = sv;
    dT[((size_t)b * NN + n) * HH + h] = dv;
  }
}

// ---------------- pass 1: per-row online softmax stats (m,l) for 8 heads ----
__global__ __launch_bounds__(256) void k_ml(
    const float* __restrict__ hg, int r,
    const float* __restrict__ sT, const float* __restrict__ dT,
    float* __restrict__ mT, float* __restrict__ lT) {
  int bi = blockIdx.x;                 // over BSZ*NN
  int i = bi & (NN - 1);
  int b = bi >> 11;
  int t = threadIdx.x;
  float sv[HH], m[HH], l[HH];
  const float* sp = sT + ((size_t)b * NN + i) * HH;
#pragma unroll
  for (int h = 0; h < HH; ++h) { sv[h] = sp[h]; m[h] = -1e30f; l[h] = 0.f; }
  const float* arow = hg + ((size_t)(b * NADJ + r) * NN + i) * NN;
  for (int j = t; j < NN; j += 256) {
    float a = arow[j];
    if (a > 0.f) {
      const float* dp = dT + ((size_t)b * NN + j) * HH;
      float4 dA = *(const float4*)dp;
      float4 dB = *(const float4*)(dp + 4);
      float dv[8] = {dA.x, dA.y, dA.z, dA.w, dB.x, dB.y, dB.z, dB.w};
#pragma unroll
      for (int h = 0; h < HH; ++h) {
        float x = sv[h] + dv[h];
        x = x > 0.f ? x : 0.2f * x;
        if (x > m[h]) { l[h] = l[h] * __expf(m[h] - x) + 1.f; m[h] = x; }
        else          { l[h] += __expf(x - m[h]); }
      }
    }
  }
#pragma unroll
  for (int h = 0; h < HH; ++h) {
    for (int off = 32; off; off >>= 1) {
      float mo = __shfl_xor(m[h], off), lo = __shfl_xor(l[h], off);
      float mn = fmaxf(m[h], mo);
      l[h] = l[h] * __expf(m[h] - mn) + lo * __expf(mo - mn);
      m[h] = mn;
    }
  }
  __shared__ float sm[4][HH], sl[4][HH];
  int wid = t >> 6, lane = t & 63;
  if (lane == 0) {
#pragma unroll
    for (int h = 0; h < HH; ++h) { sm[wid][h] = m[h]; sl[wid][h] = l[h]; }
  }
  __syncthreads();
  if (t < HH) {
    float M = sm[0][t], L = sl[0][t];
#pragma unroll
    for (int w = 1; w < 4; ++w) {
      float mo = sm[w][t], lo = sl[w][t];
      float mn = fmaxf(M, mo);
      L = L * __expf(M - mn) + lo * __expf(mo - mn);
      M = mn;
    }
    mT[((size_t)b * NN + i) * HH + t] = M;
    lT[((size_t)b * NN + i) * HH + t] = L;
  }
}

// ---------------- pass 2: out[b,h,i,:] = sum_j w_ij * hp[b,h,j,:] / l_i ------
__global__ __launch_bounds__(256) void k_pv(
    const float* __restrict__ hg, int r,
    const float* __restrict__ hp, const float* __restrict__ sT,
    const float* __restrict__ dT, const float* __restrict__ mT,
    const float* __restrict__ lT, float* __restrict__ outp) {
  const int IT = 64, JT = 64;
  __shared__ float hp_lds[JT][64];
  __shared__ float w_lds[IT][65];
  __shared__ float d_lds[JT];
  __shared__ float si[IT], mi[IT];
  int i0 = blockIdx.x * IT, h = blockIdx.y, b = blockIdx.z;
  int t = threadIdx.x;
  if (t < IT) {
    si[t] = sT[((size_t)b * NN + i0 + t) * HH + h];
    mi[t] = mT[((size_t)b * NN + i0 + t) * HH + h];
  }
  int c4 = (t & 15) * 4, r4 = (t >> 4) * 4;
  float acc[16] = {};
  const float* hpb  = hp + ((size_t)b * HH + h) * (size_t)NN * 64;
  const float* adjb = hg + (size_t)(b * NADJ + r) * (size_t)NN * NN;
  for (int j0 = 0; j0 < NN; j0 += JT) {
    __syncthreads();
    if (t < JT) d_lds[t] = dT[((size_t)b * NN + j0 + t) * HH + h];
#pragma unroll
    for (int q = 0; q < 4; ++q) {
      int idx = (t + 256 * q) * 4;
      int jj = idx >> 6, cc = idx & 63;
      *(float4*)&hp_lds[jj][cc] = *(const float4*)&hpb[(size_t)(j0 + jj) * 64 + cc];
    }
    __syncthreads();
#pragma unroll
    for (int q = 0; q < 16; ++q) {
      int e = t + 256 * q;
      int il = e >> 6, jj = e & 63;
      float a = adjb[(size_t)(i0 + il) * NN + j0 + jj];
      float wv = 0.f;
      if (a > 0.f) {
        float x = si[il] + d_lds[jj];
        x = x > 0.f ? x : 0.2f * x;
        wv = __expf(x - mi[il]);
      }
      w_lds[il][jj] = wv;
    }
    __syncthreads();
#pragma unroll 4
    for (int jj = 0; jj < JT; ++jj) {
      float4 hv = *(const float4*)&hp_lds[jj][c4];
#pragma unroll
      for (int rr = 0; rr < 4; ++rr) {
        float wv = w_lds[r4 + rr][jj];
        acc[rr * 4 + 0] += wv * hv.x;
        acc[rr * 4 + 1] += wv * hv.y;
        acc[rr * 4 + 2] += wv * hv.z;
        acc[rr * 4 + 3] += wv * hv.w;
      }
    }
  }
#pragma unroll
  for (int rr = 0; rr < 4; ++rr) {
    int il = r4 + rr;
    float linv = 1.0f / lT[((size_t)b * NN + i0 + il) * HH + h];
    float4 o = {acc[rr * 4 + 0] * linv, acc[rr * 4 + 1] * linv,
                acc[rr * 4 + 2] * linv, acc[rr * 4 + 3] * linv};
    *(float4*)&outp[(((size_t)b * HH + h) * (size_t)NN + i0 + il) * 64 + c4] = o;
  }
}

// ---------------- transpose (b,h,n,o)->(b,n,h*64+o) + elu --------------------
__global__ __launch_bounds__(256) void k_trans_elu(
    const float* __restrict__ in, float* __restrict__ outp) {
  int idx = blockIdx.x * 256 + threadIdx.x;   // over BSZ*HH*NN*64
  int o = idx & 63;
  int rest = idx >> 6;
  int n = rest & (NN - 1);
  int bh = rest >> 11;
  int h = bh & (HH - 1);
  int b = bh >> 3;
  float v = in[idx];
  v = v > 0.f ? v : (__expf(v) - 1.f);
  outp[((size_t)b * NN + n) * K1 + h * 64 + o] = v;
}

// ---------------- mean over heads → seq[b,n,r,:] ----------------------------
__global__ __launch_bounds__(256) void k_mean(
    const float* __restrict__ in, float* __restrict__ seq, int r) {
  int idx = blockIdx.x * 256 + threadIdx.x;   // over BSZ*NN*64
  int o = idx & 63;
  int rest = idx >> 6;
  int n = rest & (NN - 1);
  int b = rest >> 11;
  float acc = 0.f;
#pragma unroll
  for (int h = 0; h < HH; ++h)
    acc += in[(((size_t)b * HH + h) * NN + n) * 64 + o];
  seq[(((size_t)b * NN + n) * NADJ + r) * 64 + o] = acc * 0.125f;
}

// ---------------- final fusion + log_softmax --------------------------------
__global__ __launch_bounds__(256) void k_fuse(
    const float* __restrict__ fp, const float* __restrict__ seq,
    const float* __restrict__ aw2, const float* __restrict__ am,
    float* __restrict__ outp) {
  __shared__ float w2[64][65];
  __shared__ float amv[64];
  __shared__ float seq_lds[4][NADJ][64];
  int t = threadIdx.x;
#pragma unroll
  for (int q = 0; q < 16; ++q) {
    int e = t + 256 * q;
    w2[e >> 6][e & 63] = aw2[e];
  }
  if (t < 64) amv[t] = am[t];
  int wid = t >> 6, lane = t & 63;
  int bn = blockIdx.x * 4 + wid;               // over BSZ*NN
  float s0 = seq[((size_t)bn * NADJ + 0) * 64 + lane];
  float s1 = seq[((size_t)bn * NADJ + 1) * 64 + lane];
  seq_lds[wid][0][lane] = s0;
  seq_lds[wid][1][lane] = s1;
  __syncthreads();
  float f = fp[(size_t)bn * 64 + lane];
  float q0 = f, q1 = f;
  for (int k = 0; k < 64; ++k) {
    float wv = w2[k][lane];
    q0 += seq_lds[wid][0][k] * wv;
    q1 += seq_lds[wid][1][k] * wv;
  }
  q0 = tanhf(q0); q1 = tanhf(q1);
  float sc0 = q0 * amv[lane], sc1 = q1 * amv[lane];
  for (int off = 32; off; off >>= 1) {
    sc0 += __shfl_xor(sc0, off);
    sc1 += __shfl_xor(sc1, off);
  }
  float mx = fmaxf(sc0, sc1);
  float e0 = __expf(sc0 - mx), e1 = __expf(sc1 - mx);
  float inv = 1.f / (e0 + e1);
  float fu = (e0 * inv) * s0 + (e1 * inv) * s1;
  float m = fu;
  for (int off = 32; off; off >>= 1) m = fmaxf(m, __shfl_xor(m, off));
  float ex = __expf(fu - m);
  float ssum = ex;
  for (int off = 32; off; off >>= 1) ssum += __shfl_xor(ssum, off);
  outp[(size_t)bn * 64 + lane] = fu - m - __logf(ssum);
}

extern "C" void kernel_launch(void* const* d_in, const int* in_sizes, int n_in,
                              void* d_out, int out_size, void* d_ws, size_t ws_size,
                              hipStream_t stream) {
  (void)in_sizes; (void)n_in; (void)out_size; (void)ws_size;
  const float* hg   = (const float*)d_in[0];
  const int*   vert = (const int*)d_in[1];
  const float* lemb = (const float*)d_in[2];
  const float* emb0 = (const float*)d_in[3];
  const float* emb1 = (const float*)d_in[4];
  const float* w_l0 = (const float*)d_in[5];
  const float* as0  = (const float*)d_in[6];
  const float* ad0  = (const float*)d_in[7];
  const float* w_l1 = (const float*)d_in[8];
  const float* as1  = (const float*)d_in[9];
  const float* ad1  = (const float*)d_in[10];
  const float* aw1  = (const float*)d_in[11];
  const float* aw2  = (const float*)d_in[12];
  const float* am   = (const float*)d_in[13];
  float* out = (float*)d_out;
  float* ws = (float*)d_ws;

  float* feat  = ws;                       // BSZ*NN*NF        = 786432
  float* hp    = feat + 786432;            // BSZ*HH*NN*64     = 2097152
  float* aout  = hp + 2097152;             // BSZ*HH*NN*64     = 2097152
  float* hmid  = aout + 2097152;           // BSZ*NN*K1        = 2097152
  float* sT    = hmid + 2097152;           // BSZ*NN*HH        = 32768
  float* dT    = sT + 32768;
  float* mT    = dT + 32768;
  float* lT    = mT + 32768;
  float* seq   = lT + 32768;               // BSZ*NN*NADJ*64   = 524288
  float* fproj = seq + 524288;             // BSZ*NN*64        = 262144

  k_build_feat<<<(BSZ * NN * NF) / 256, 256, 0, stream>>>(vert, lemb, emb0, emb1, feat);
  k_gemm<NF><<<dim3(NN / 64, 1, BSZ), 256, 0, stream>>>(feat, aw1, fproj, 1);

  for (int r = 0; r < NADJ; ++r) {
    // layer 0
    k_gemm<NF><<<dim3(NN / 64, HH, BSZ), 256, 0, stream>>>(
        feat, w_l0 + (size_t)r * HH * NF * 64, hp, HH);
    k_sd<<<BSZ * HH * NN / 4, 256, 0, stream>>>(hp, as0 + r * HH * 64, ad0 + r * HH * 64, sT, dT);
    k_ml<<<BSZ * NN, 256, 0, stream>>>(hg, r, sT, dT, mT, lT);
    k_pv<<<dim3(NN / 64, HH, BSZ), 256, 0, stream>>>(hg, r, hp, sT, dT, mT, lT, aout);
    k_trans_elu<<<(BSZ * HH * NN * 64) / 256, 256, 0, stream>>>(aout, hmid);
    // layer 1
    k_gemm<K1><<<dim3(NN / 64, HH, BSZ), 256, 0, stream>>>(
        hmid, w_l1 + (size_t)r * HH * K1 * 64, hp, HH);
    k_sd<<<BSZ * HH * NN / 4, 256, 0, stream>>>(hp, as1 + r * HH * 64, ad1 + r * HH * 64, sT, dT);
    k_ml<<<BSZ * NN, 256, 0, stream>>>(hg, r, sT, dT, mT, lT);
    k_pv<<<dim3(NN / 64, HH, BSZ), 256, 0, stream>>>(hg, r, hp, sT, dT, mT, lT, aout);
    k_mean<<<(BSZ * NN * 64) / 256, 256, 0, stream>>>(aout, seq, r);
  }
  k_fuse<<<BSZ * NN / 4, 256, 0, stream>>>(fproj, seq, aw2, am, out);
}

// Round 2
// 655.969 us; speedup vs baseline: 2.3749x; 2.3749x over previous
//
#include <hip/hip_runtime.h>
#include <hip/hip_bf16.h>

#define BSZ 2
#define NADJ 2
#define NN 2048
#define DE 64
#define HH 8
#define F1 64
#define NF 192   // 3*DE
#define K1 512   // HH*F1

typedef short s16x8 __attribute__((ext_vector_type(8)));
typedef unsigned short u16x8 __attribute__((ext_vector_type(8)));
typedef float f32x4 __attribute__((ext_vector_type(4)));

__device__ __forceinline__ unsigned short f2b(float x) {
  union { float f; unsigned int u; } v; v.f = x;
  unsigned int r = v.u + 0x7fffu + ((v.u >> 16) & 1u);
  return (unsigned short)(r >> 16);
}

// ---------------- build feat = [emb0[v], emb1[v], local_emb] ----------------
__global__ __launch_bounds__(256) void k_build_feat(
    const int* __restrict__ vert, const float* __restrict__ lemb,
    const float* __restrict__ emb0, const float* __restrict__ emb1,
    float* __restrict__ feat) {
  int idx = blockIdx.x * 256 + threadIdx.x;          // over BSZ*NN*NF
  int f = idx % NF;
  int bn = idx / NF;
  int v = vert[bn];
  float val;
  if (f < 64)       val = emb0[v * 64 + f];
  else if (f < 128) val = emb1[v * 64 + (f - 64)];
  else              val = lemb[bn * 64 + (f - 128)];
  feat[idx] = val;
}

// ---------------- per-head GEMM: out[b,h,n,o] = sum_k in[b,n,k]*w[h,k,o] ----
template <int K>
__global__ __launch_bounds__(256) void k_gemm(
    const float* __restrict__ in, const float* __restrict__ w,
    float* __restrict__ outp, int nheads) {
  __shared__ float a_lds[64][68];   // padded; fp32 staging via float4
  __shared__ float w_lds[64][64];
  int tile = blockIdx.x, h = blockIdx.y, b = blockIdx.z;
  int t = threadIdx.x;
  int row0 = tile * 64;
  int c4 = (t & 15) * 4, r4 = (t >> 4) * 4;
  float acc[16] = {};
  const float* inb = in + (size_t)b * NN * K + (size_t)row0 * K;
  const float* wb  = w + (size_t)h * K * 64;
  for (int k0 = 0; k0 < K; k0 += 64) {
    __syncthreads();
#pragma unroll
    for (int q = 0; q < 4; ++q) {
      int idx = (t + 256 * q) * 4;
      int rr = idx >> 6, kk = idx & 63;
      *(float4*)&a_lds[rr][kk] = *(const float4*)&inb[(size_t)rr * K + k0 + kk];
      *(float4*)&w_lds[rr][kk] = *(const float4*)&wb[(size_t)(k0 + rr) * 64 + kk];
    }
    __syncthreads();
#pragma unroll 4
    for (int kk = 0; kk < 64; ++kk) {
      float4 wv = *(const float4*)&w_lds[kk][c4];
#pragma unroll
      for (int rr = 0; rr < 4; ++rr) {
        float av = a_lds[r4 + rr][kk];
        acc[rr * 4 + 0] += av * wv.x;
        acc[rr * 4 + 1] += av * wv.y;
        acc[rr * 4 + 2] += av * wv.z;
        acc[rr * 4 + 3] += av * wv.w;
      }
    }
  }
  size_t ob = (((size_t)b * nheads + h) * NN + row0 + r4) * 64 + c4;
#pragma unroll
  for (int rr = 0; rr < 4; ++rr) {
    float4 o = {acc[rr * 4 + 0], acc[rr * 4 + 1], acc[rr * 4 + 2], acc[rr * 4 + 3]};
    *(float4*)&outp[ob + (size_t)rr * 64] = o;
  }
}

// ---------------- transpose-cast hp[b,h,j,o] fp32 -> hpT[b,h,o,j] bf16 ------
__global__ __launch_bounds__(256) void k_hp_t(
    const float* __restrict__ hp, unsigned short* __restrict__ hpT) {
  __shared__ unsigned short tr[64][72];
  int j0 = blockIdx.x * 64;
  int plane = blockIdx.y;                  // b*HH + h
  const float* src = hp + (size_t)plane * NN * 64;
  unsigned short* dst = hpT + (size_t)plane * 64 * NN;
  int t = threadIdx.x;
#pragma unroll
  for (int q = 0; q < 4; ++q) {
    int e = q * 256 + t;
    int jr = e >> 4, oc = (e & 15) * 4;
    float4 v = *(const float4*)&src[(size_t)(j0 + jr) * 64 + oc];
    tr[oc + 0][jr] = f2b(v.x);
    tr[oc + 1][jr] = f2b(v.y);
    tr[oc + 2][jr] = f2b(v.z);
    tr[oc + 3][jr] = f2b(v.w);
  }
  __syncthreads();
#pragma unroll
  for (int q = 0; q < 2; ++q) {
    int e = q * 256 + t;
    int o = e >> 3, j8 = (e & 7) * 8;
    *(u16x8*)&dst[(size_t)o * NN + j0 + j8] = *(const u16x8*)&tr[o][j8];
  }
}

// ---------------- s,d vectors: s[b,n,h] = sum_o tanh(hp[b,h,n,o])*a_src[h,o] -
__global__ __launch_bounds__(256) void k_sd(
    const float* __restrict__ hp, const float* __restrict__ a_src,
    const float* __restrict__ a_dst, float* __restrict__ sT, float* __restrict__ dT) {
  int gw = blockIdx.x * 4 + (threadIdx.x >> 6);   // over BSZ*HH*NN (b,h,n)
  int lane = threadIdx.x & 63;
  int n = gw & (NN - 1);
  int bh = gw >> 11;
  int h = bh & (HH - 1);
  int b = bh >> 3;
  float v = tanhf(hp[(size_t)gw * 64 + lane]);
  float sv = v * a_src[h * 64 + lane];
  float dv = v * a_dst[h * 64 + lane];
  for (int off = 32; off; off >>= 1) {
    sv += __shfl_down(sv, off);
    dv += __shfl_down(dv, off);
  }
  if (lane == 0) {
    sT[((size_t)b * NN + n) * HH + h] = sv;
    dT[((size_t)b * NN + n) * HH + h] = dv;
  }
}

// ---------------- pass 1: per-row online softmax stats (m,l) for 8 heads ----
__global__ __launch_bounds__(256) void k_ml(
    const float* __restrict__ hg, int r,
    const float* __restrict__ sT, const float* __restrict__ dT,
    float* __restrict__ mT, float* __restrict__ lT) {
  int bi = blockIdx.x;                 // over BSZ*NN
  int i = bi & (NN - 1);
  int b = bi >> 11;
  int t = threadIdx.x;
  float sv[HH], m[HH], l[HH];
  const float* sp = sT + ((size_t)b * NN + i) * HH;
#pragma unroll
  for (int h = 0; h < HH; ++h) { sv[h] = sp[h]; m[h] = -1e30f; l[h] = 0.f; }
  const float* arow = hg + ((size_t)(b * NADJ + r) * NN + i) * NN;
  for (int j = t; j < NN; j += 256) {
    float a = arow[j];
    if (a > 0.f) {
      const float* dp = dT + ((size_t)b * NN + j) * HH;
      float4 dA = *(const float4*)dp;
      float4 dB = *(const float4*)(dp + 4);
      float dv[8] = {dA.x, dA.y, dA.z, dA.w, dB.x, dB.y, dB.z, dB.w};
#pragma unroll
      for (int h = 0; h < HH; ++h) {
        float x = sv[h] + dv[h];
        x = x > 0.f ? x : 0.2f * x;
        if (x > m[h]) { l[h] = l[h] * __expf(m[h] - x) + 1.f; m[h] = x; }
        else          { l[h] += __expf(x - m[h]); }
      }
    }
  }
#pragma unroll
  for (int h = 0; h < HH; ++h) {
    for (int off = 32; off; off >>= 1) {
      float mo = __shfl_xor(m[h], off), lo = __shfl_xor(l[h], off);
      float mn = fmaxf(m[h], mo);
      l[h] = l[h] * __expf(m[h] - mn) + lo * __expf(mo - mn);
      m[h] = mn;
    }
  }
  __shared__ float sm[4][HH], sl[4][HH];
  int wid = t >> 6, lane = t & 63;
  if (lane == 0) {
#pragma unroll
    for (int h = 0; h < HH; ++h) { sm[wid][h] = m[h]; sl[wid][h] = l[h]; }
  }
  __syncthreads();
  if (t < HH) {
    float M = sm[0][t], L = sl[0][t];
#pragma unroll
    for (int w = 1; w < 4; ++w) {
      float mo = sm[w][t], lo = sl[w][t];
      float mn = fmaxf(M, mo);
      L = L * __expf(M - mn) + lo * __expf(mo - mn);
      M = mn;
    }
    mT[((size_t)b * NN + i) * HH + t] = M;
    lT[((size_t)b * NN + i) * HH + t] = L;
  }
}

// ---------------- pass 2 (MFMA): out[b,h,i,:] = sum_j w_ij * hp[b,h,j,:]/l_i -
__global__ __launch_bounds__(256) void k_pv(
    const float* __restrict__ hg, int r,
    const unsigned short* __restrict__ hpT, const float* __restrict__ sT,
    const float* __restrict__ dT, const float* __restrict__ mT,
    const float* __restrict__ lT, float* __restrict__ outp) {
  __shared__ unsigned short w_lds[64][72];   // bf16 attn weights, +8 pad
  __shared__ unsigned short hp_lds[64][72];  // bf16 hpT tile [o][j]
  __shared__ float d_lds[64];
  __shared__ float si[64], mi[64];
  int i0 = blockIdx.x * 64, h = blockIdx.y, b = blockIdx.z;
  int t = threadIdx.x;
  int lane = t & 63, wv = t >> 6;
  if (t < 64) {
    si[t] = sT[((size_t)b * NN + i0 + t) * HH + h];
    mi[t] = mT[((size_t)b * NN + i0 + t) * HH + h];
  }
  const unsigned short* hpTb = hpT + (size_t)(b * HH + h) * 64 * NN;
  const float* adjb = hg + (size_t)(b * NADJ + r) * (size_t)NN * NN;
  f32x4 acc[4] = {};
  float4 adjr[4];
#pragma unroll
  for (int q = 0; q < 4; ++q) {
    int e4 = q * 256 + t;
    int il = e4 >> 4, j4 = (e4 & 15) * 4;
    adjr[q] = *(const float4*)&adjb[(size_t)(i0 + il) * NN + j4];
  }
  for (int j0 = 0; j0 < NN; j0 += 64) {
    // ---- A1: stage d + hpT tile ----
    if (t < 64) d_lds[t] = dT[((size_t)b * NN + j0 + t) * HH + h];
#pragma unroll
    for (int q = 0; q < 2; ++q) {
      int e = q * 256 + t;
      int o = e >> 3, j8 = (e & 7) * 8;
      *(u16x8*)&hp_lds[o][j8] = *(const u16x8*)&hpTb[(size_t)o * NN + j0 + j8];
    }
    __syncthreads();
    // ---- A2: prefetch next adj tile; compute bf16 weight tile ----
    float4 adjn[4];
    if (j0 + 64 < NN) {
#pragma unroll
      for (int q = 0; q < 4; ++q) {
        int e4 = q * 256 + t;
        int il = e4 >> 4, j4 = (e4 & 15) * 4;
        adjn[q] = *(const float4*)&adjb[(size_t)(i0 + il) * NN + (j0 + 64) + j4];
      }
    }
#pragma unroll
    for (int q = 0; q < 4; ++q) {
      int e4 = q * 256 + t;
      int il = e4 >> 4, j4 = (e4 & 15) * 4;
      float sv = si[il], mv = mi[il];
      const float* ap = (const float*)&adjr[q];
      unsigned int pk[2];
#pragma unroll
      for (int p = 0; p < 2; ++p) {
        unsigned short u0, u1;
#pragma unroll
        for (int c = 0; c < 2; ++c) {
          int cc = p * 2 + c;
          float x = sv + d_lds[j4 + cc];
          x = x > 0.f ? x : 0.2f * x;
          float wval = (ap[cc] > 0.f) ? __expf(x - mv) : 0.f;
          if (c == 0) u0 = f2b(wval); else u1 = f2b(wval);
        }
        pk[p] = (unsigned int)u0 | ((unsigned int)u1 << 16);
      }
      *(uint2*)&w_lds[il][j4] = *(uint2*)pk;
    }
    __syncthreads();
    // ---- B: MFMA ----
    {
      int rA = wv * 16 + (lane & 15);
      int kb = 8 * (lane >> 4);
#pragma unroll
      for (int kk = 0; kk < 2; ++kk) {
        s16x8 av = *(const s16x8*)&w_lds[rA][kk * 32 + kb];
#pragma unroll
        for (int nf = 0; nf < 4; ++nf) {
          s16x8 bv = *(const s16x8*)&hp_lds[nf * 16 + (lane & 15)][kk * 32 + kb];
          acc[nf] = __builtin_amdgcn_mfma_f32_16x16x32_bf16(av, bv, acc[nf], 0, 0, 0);
        }
      }
    }
    __syncthreads();
    if (j0 + 64 < NN) {
#pragma unroll
      for (int q = 0; q < 4; ++q) adjr[q] = adjn[q];
    }
  }
  // ---- epilogue: D layout col=lane&15, row=(lane>>4)*4+reg ----
  int col = lane & 15;
  int r0 = wv * 16 + (lane >> 4) * 4;
#pragma unroll
  for (int reg = 0; reg < 4; ++reg) {
    int m = r0 + reg;
    float linv = 1.0f / lT[((size_t)b * NN + i0 + m) * HH + h];
    size_t ob = (((size_t)b * HH + h) * NN + i0 + m) * 64;
#pragma unroll
    for (int nf = 0; nf < 4; ++nf) {
      outp[ob + nf * 16 + col] = acc[nf][reg] * linv;
    }
  }
}

// ---------------- transpose (b,h,n,o)->(b,n,h*64+o) + elu --------------------
__global__ __launch_bounds__(256) void k_trans_elu(
    const float* __restrict__ in, float* __restrict__ outp) {
  int idx = blockIdx.x * 256 + threadIdx.x;   // over BSZ*HH*NN*64
  int o = idx & 63;
  int rest = idx >> 6;
  int n = rest & (NN - 1);
  int bh = rest >> 11;
  int h = bh & (HH - 1);
  int b = bh >> 3;
  float v = in[idx];
  v = v > 0.f ? v : (__expf(v) - 1.f);
  outp[((size_t)b * NN + n) * K1 + h * 64 + o] = v;
}

// ---------------- mean over heads → seq[b,n,r,:] ----------------------------
__global__ __launch_bounds__(256) void k_mean(
    const float* __restrict__ in, float* __restrict__ seq, int r) {
  int idx = blockIdx.x * 256 + threadIdx.x;   // over BSZ*NN*64
  int o = idx & 63;
  int rest = idx >> 6;
  int n = rest & (NN - 1);
  int b = rest >> 11;
  float acc = 0.f;
#pragma unroll
  for (int h = 0; h < HH; ++h)
    acc += in[(((size_t)b * HH + h) * NN + n) * 64 + o];
  seq[(((size_t)b * NN + n) * NADJ + r) * 64 + o] = acc * 0.125f;
}

// ---------------- final fusion + log_softmax --------------------------------
__global__ __launch_bounds__(256) void k_fuse(
    const float* __restrict__ fp, const float* __restrict__ seq,
    const float* __restrict__ aw2, const float* __restrict__ am,
    float* __restrict__ outp) {
  __shared__ float w2[64][65];
  __shared__ float amv[64];
  __shared__ float seq_lds[4][NADJ][64];
  int t = threadIdx.x;
#pragma unroll
  for (int q = 0; q < 16; ++q) {
    int e = t + 256 * q;
    w2[e >> 6][e & 63] = aw2[e];
  }
  if (t < 64) amv[t] = am[t];
  int wid = t >> 6, lane = t & 63;
  int bn = blockIdx.x * 4 + wid;               // over BSZ*NN
  float s0 = seq[((size_t)bn * NADJ + 0) * 64 + lane];
  float s1 = seq[((size_t)bn * NADJ + 1) * 64 + lane];
  seq_lds[wid][0][lane] = s0;
  seq_lds[wid][1][lane] = s1;
  __syncthreads();
  float f = fp[(size_t)bn * 64 + lane];
  float q0 = f, q1 = f;
  for (int k = 0; k < 64; ++k) {
    float wv = w2[k][lane];
    q0 += seq_lds[wid][0][k] * wv;
    q1 += seq_lds[wid][1][k] * wv;
  }
  q0 = tanhf(q0); q1 = tanhf(q1);
  float sc0 = q0 * amv[lane], sc1 = q1 * amv[lane];
  for (int off = 32; off; off >>= 1) {
    sc0 += __shfl_xor(sc0, off);
    sc1 += __shfl_xor(sc1, off);
  }
  float mx = fmaxf(sc0, sc1);
  float e0 = __expf(sc0 - mx), e1 = __expf(sc1 - mx);
  float inv = 1.f / (e0 + e1);
  float fu = (e0 * inv) * s0 + (e1 * inv) * s1;
  float m = fu;
  for (int off = 32; off; off >>= 1) m = fmaxf(m, __shfl_xor(m, off));
  float ex = __expf(fu - m);
  float ssum = ex;
  for (int off = 32; off; off >>= 1) ssum += __shfl_xor(ssum, off);
  outp[(size_t)bn * 64 + lane] = fu - m - __logf(ssum);
}

extern "C" void kernel_launch(void* const* d_in, const int* in_sizes, int n_in,
                              void* d_out, int out_size, void* d_ws, size_t ws_size,
                              hipStream_t stream) {
  (void)in_sizes; (void)n_in; (void)out_size; (void)ws_size;
  const float* hg   = (const float*)d_in[0];
  const int*   vert = (const int*)d_in[1];
  const float* lemb = (const float*)d_in[2];
  const float* emb0 = (const float*)d_in[3];
  const float* emb1 = (const float*)d_in[4];
  const float* w_l0 = (const float*)d_in[5];
  const float* as0  = (const float*)d_in[6];
  const float* ad0  = (const float*)d_in[7];
  const float* w_l1 = (const float*)d_in[8];
  const float* as1  = (const float*)d_in[9];
  const float* ad1  = (const float*)d_in[10];
  const float* aw1  = (const float*)d_in[11];
  const float* aw2  = (const float*)d_in[12];
  const float* am   = (const float*)d_in[13];
  float* out = (float*)d_out;
  float* ws = (float*)d_ws;

  float* feat  = ws;                       // BSZ*NN*NF        = 786432
  float* hp    = feat + 786432;            // BSZ*HH*NN*64     = 2097152
  float* aout  = hp + 2097152;             // BSZ*HH*NN*64     = 2097152
  float* hmid  = aout + 2097152;           // BSZ*NN*K1        = 2097152
  float* sT    = hmid + 2097152;           // BSZ*NN*HH        = 32768
  float* dT    = sT + 32768;
  float* mT    = dT + 32768;
  float* lT    = mT + 32768;
  float* seq   = lT + 32768;               // BSZ*NN*NADJ*64   = 524288
  float* fproj = seq + 524288;             // BSZ*NN*64        = 262144
  // hpT (bf16, 4MB) aliases hmid (8MB): hmid is dead whenever hpT is live
  // (layer0: hmid written only after k_pv; layer1: hmid consumed by k_gemm<K1>
  //  which completes before k_hp_t in stream order).
  unsigned short* hpT = (unsigned short*)hmid;

  k_build_feat<<<(BSZ * NN * NF) / 256, 256, 0, stream>>>(vert, lemb, emb0, emb1, feat);
  k_gemm<NF><<<dim3(NN / 64, 1, BSZ), 256, 0, stream>>>(feat, aw1, fproj, 1);

  for (int r = 0; r < NADJ; ++r) {
    // layer 0
    k_gemm<NF><<<dim3(NN / 64, HH, BSZ), 256, 0, stream>>>(
        feat, w_l0 + (size_t)r * HH * NF * 64, hp, HH);
    k_hp_t<<<dim3(NN / 64, BSZ * HH), 256, 0, stream>>>(hp, hpT);
    k_sd<<<BSZ * HH * NN / 4, 256, 0, stream>>>(hp, as0 + r * HH * 64, ad0 + r * HH * 64, sT, dT);
    k_ml<<<BSZ * NN, 256, 0, stream>>>(hg, r, sT, dT, mT, lT);
    k_pv<<<dim3(NN / 64, HH, BSZ), 256, 0, stream>>>(hg, r, hpT, sT, dT, mT, lT, aout);
    k_trans_elu<<<(BSZ * HH * NN * 64) / 256, 256, 0, stream>>>(aout, hmid);
    // layer 1
    k_gemm<K1><<<dim3(NN / 64, HH, BSZ), 256, 0, stream>>>(
        hmid, w_l1 + (size_t)r * HH * K1 * 64, hp, HH);
    k_hp_t<<<dim3(NN / 64, BSZ * HH), 256, 0, stream>>>(hp, hpT);
    k_sd<<<BSZ * HH * NN / 4, 256, 0, stream>>>(hp, as1 + r * HH * 64, ad1 + r * HH * 64, sT, dT);
    k_ml<<<BSZ * NN, 256, 0, stream>>>(hg, r, sT, dT, mT, lT);
    k_pv<<<dim3(NN / 64, HH, BSZ), 256, 0, stream>>>(hg, r, hpT, sT, dT, mT, lT, aout);
    k_mean<<<(BSZ * NN * 64) / 256, 256, 0, stream>>>(aout, seq, r);
  }
  k_fuse<<<BSZ * NN / 4, 256, 0, stream>>>(fproj, seq, aw2, am, out);
}

// Round 3
// 289.569 us; speedup vs baseline: 5.3800x; 2.2653x over previous
//
#include <hip/hip_runtime.h>
#include <hip/hip_bf16.h>

#define BSZ 2
#define NADJ 2
#define NN 2048
#define DE 64
#define HH 8
#define F1 64
#define NF 192   // 3*DE
#define K1 512   // HH*F1
#define LOG2E 1.4426950408889634f

typedef short s16x8 __attribute__((ext_vector_type(8)));
typedef unsigned short u16x8 __attribute__((ext_vector_type(8)));
typedef float f32x4 __attribute__((ext_vector_type(4)));

__device__ __forceinline__ unsigned short f2b(float x) {
  union { float f; unsigned int u; } v; v.f = x;
  unsigned int r = v.u + 0x7fffu + ((v.u >> 16) & 1u);
  return (unsigned short)(r >> 16);
}

// ---- 64x64 bf16 tile staging helpers (XOR-swizzled LDS, 128B rows) ---------
// logical [row][byte] -> physical byte = row*128 + (byte ^ ((row&7)<<4))
__device__ __forceinline__ void tile_load(const unsigned short* g, int rowstride,
                                          int t, u16x8& a, u16x8& b) {
  int o = t >> 2, j = (t & 3) * 16;
  const unsigned short* p = g + (size_t)o * rowstride + j;
  a = *(const u16x8*)p;
  b = *(const u16x8*)(p + 8);
}
__device__ __forceinline__ void tile_store(unsigned short* lds, int t, u16x8 a, u16x8 b) {
  int o = t >> 2, jb = (t & 3) * 32;
  int swz = (o & 7) << 4;
  char* base = (char*)lds + o * 128;
  *(u16x8*)(base + (jb ^ swz)) = a;
  *(u16x8*)(base + ((jb + 16) ^ swz)) = b;
}
__device__ __forceinline__ const s16x8* tile_read_ptr(const unsigned short* lds,
                                                      int row, int kbyte) {
  return (const s16x8*)((const char*)lds + row * 128 + (kbyte ^ ((row & 7) << 4)));
}

// ---------------- build feat = [emb0[v], emb1[v], local_emb] (bf16) ---------
__global__ __launch_bounds__(256) void k_build_feat(
    const int* __restrict__ vert, const float* __restrict__ lemb,
    const float* __restrict__ emb0, const float* __restrict__ emb1,
    unsigned short* __restrict__ featB) {
  int idx = blockIdx.x * 256 + threadIdx.x;          // over BSZ*NN*NF
  int f = idx % NF;
  int bn = idx / NF;
  int v = vert[bn];
  float val;
  if (f < 64)       val = emb0[v * 64 + f];
  else if (f < 128) val = emb1[v * 64 + (f - 64)];
  else              val = lemb[bn * 64 + (f - 128)];
  featB[idx] = f2b(val);
}

// ---------------- adjacency ballot bitmask ----------------------------------
__global__ __launch_bounds__(256) void k_bits(
    const float* __restrict__ hg, unsigned long long* __restrict__ bits) {
  size_t idx = (size_t)blockIdx.x * 256 + threadIdx.x;   // over BSZ*NADJ*NN*NN
  float a = hg[idx];
  unsigned long long m = __ballot(a > 0.f);
  if ((threadIdx.x & 63) == 0) bits[idx >> 6] = m;
}

// ---------------- transpose-cast src[plane][R][64] f32 -> dst[plane][64][R] bf16
__global__ __launch_bounds__(256) void k_tcast(
    const float* __restrict__ src, unsigned short* __restrict__ dst, int R) {
  __shared__ unsigned short tr[64][72];
  int k0 = blockIdx.x * 64;
  int plane = blockIdx.y;
  const float* s = src + (size_t)plane * R * 64;
  unsigned short* d = dst + (size_t)plane * 64 * R;
  int t = threadIdx.x;
#pragma unroll
  for (int q = 0; q < 4; ++q) {
    int e = q * 256 + t;
    int kr = e >> 4, oc = (e & 15) * 4;
    float4 v = *(const float4*)&s[(size_t)(k0 + kr) * 64 + oc];
    tr[oc + 0][kr] = f2b(v.x);
    tr[oc + 1][kr] = f2b(v.y);
    tr[oc + 2][kr] = f2b(v.z);
    tr[oc + 3][kr] = f2b(v.w);
  }
  __syncthreads();
#pragma unroll
  for (int q = 0; q < 2; ++q) {
    int e = q * 256 + t;
    int o = e >> 3, j8 = (e & 7) * 8;
    *(u16x8*)&d[(size_t)o * R + k0 + j8] = *(const u16x8*)&tr[o][j8];
  }
}

// ---------------- bf16 MFMA GEMM: out[b,h,n,o] = sum_k A[b,n,k]*W[h,k,o] ----
// A bf16 [b][n][K]; Bw = W^T bf16 [h][o][K]; out fp32.
template <int K>
__global__ __launch_bounds__(256) void k_gemm_bf16(
    const unsigned short* __restrict__ A, const unsigned short* __restrict__ Bw,
    float* __restrict__ outp, int nheads) {
  __shared__ unsigned short a_lds[2][64 * 64];
  __shared__ unsigned short b_lds[2][64 * 64];
  int tile = blockIdx.x, h = blockIdx.y, b = blockIdx.z;
  int t = threadIdx.x, lane = t & 63, wv = t >> 6;
  const unsigned short* Ab = A + ((size_t)b * NN + tile * 64) * K;
  const unsigned short* Bb = Bw + (size_t)h * 64 * K;
  const int NT = K / 64;
  u16x8 a0, a1, b0, b1;
  tile_load(Ab, K, t, a0, a1);
  tile_load(Bb, K, t, b0, b1);
  tile_store(a_lds[0], t, a0, a1);
  tile_store(b_lds[0], t, b0, b1);
  if (NT > 1) { tile_load(Ab + 64, K, t, a0, a1); tile_load(Bb + 64, K, t, b0, b1); }
  __syncthreads();
  f32x4 acc[4] = {};
  int rowA = wv * 16 + (lane & 15);
  int rowB0 = lane & 15;
  int kb2 = (lane >> 4) * 16;   // byte offset of k-start within 64-elem tile
  for (int it = 0; it < NT; ++it) {
    int buf = it & 1;
    if (it + 1 < NT) {
      tile_store(a_lds[buf ^ 1], t, a0, a1);
      tile_store(b_lds[buf ^ 1], t, b0, b1);
    }
    if (it + 2 < NT) {
      tile_load(Ab + (it + 2) * 64, K, t, a0, a1);
      tile_load(Bb + (it + 2) * 64, K, t, b0, b1);
    }
#pragma unroll
    for (int kk = 0; kk < 2; ++kk) {
      s16x8 av = *tile_read_ptr(a_lds[buf], rowA, kk * 64 + kb2);
#pragma unroll
      for (int nf = 0; nf < 4; ++nf) {
        s16x8 bv = *tile_read_ptr(b_lds[buf], nf * 16 + rowB0, kk * 64 + kb2);
        acc[nf] = __builtin_amdgcn_mfma_f32_16x16x32_bf16(av, bv, acc[nf], 0, 0, 0);
      }
    }
    __syncthreads();
  }
  int col = lane & 15, r0 = (lane >> 4) * 4;
  size_t ob = (((size_t)b * nheads + h) * NN + tile * 64 + wv * 16 + r0) * 64 + col;
#pragma unroll
  for (int reg = 0; reg < 4; ++reg) {
#pragma unroll
    for (int nf = 0; nf < 4; ++nf)
      outp[ob + (size_t)reg * 64 + nf * 16] = acc[nf][reg];
  }
}

// ---------------- s,d (scaled by log2e): s = sum_o tanh(hp)*a_src -----------
__global__ __launch_bounds__(256) void k_sd(
    const float* __restrict__ hp, const float* __restrict__ a_src,
    const float* __restrict__ a_dst, float* __restrict__ sT, float* __restrict__ dT) {
  int gw = blockIdx.x * 4 + (threadIdx.x >> 6);   // over BSZ*HH*NN (b,h,n)
  int lane = threadIdx.x & 63;
  int n = gw & (NN - 1);
  int bh = gw >> 11;
  int h = bh & (HH - 1);
  int b = bh >> 3;
  float v = tanhf(hp[(size_t)gw * 64 + lane]);
  float sv = v * a_src[h * 64 + lane];
  float dv = v * a_dst[h * 64 + lane];
  for (int off = 32; off; off >>= 1) {
    sv += __shfl_down(sv, off);
    dv += __shfl_down(dv, off);
  }
  if (lane == 0) {
    sT[((size_t)b * NN + n) * HH + h] = sv * LOG2E;
    dT[((size_t)b * NN + n) * HH + h] = dv * LOG2E;
  }
}

// ---------------- PV (MFMA, fused l): out = (sum_j w_ij hp_j) / sum_j w_ij --
// w_ij = adj_ij * exp2(leaky(s'_i + d'_j)); A-frags computed in registers.
__global__ __launch_bounds__(256) void k_pv(
    const unsigned long long* __restrict__ bits, int r,
    const unsigned short* __restrict__ hpT,      // [b*HH+h][o=64][j=NN] bf16
    const float* __restrict__ sT, const float* __restrict__ dT,
    float* __restrict__ outp) {
  __shared__ unsigned short hp_lds[2][64 * 64];
  __shared__ float d_lds[2][64];
  __shared__ float l_lds[64];
  int i0 = blockIdx.x * 64, h = blockIdx.y, b = blockIdx.z;
  int t = threadIdx.x, lane = t & 63, wv = t >> 6;
  int rowi = wv * 16 + (lane & 15);
  int kb = (lane >> 4) * 8;
  float sreg = sT[((size_t)b * NN + i0 + rowi) * HH + h];
  const unsigned long long* brow =
      bits + ((size_t)(b * NADJ + r) * NN + i0 + rowi) * (NN / 64);
  const unsigned short* hpTb = hpT + (size_t)(b * HH + h) * 64 * NN;
  const float* dTb = dT + (size_t)b * NN * HH + h;
  f32x4 acc[4] = {};
  float suml = 0.f;

  // prologue: tile 0 -> LDS buf0; tile 1 -> regs
  u16x8 ra, rb;
  float rd;
  tile_load(hpTb, NN, t, ra, rb);
  rd = (t < 64) ? dTb[(size_t)t * HH] : 0.f;
  tile_store(hp_lds[0], t, ra, rb);
  if (t < 64) d_lds[0][t] = rd;
  tile_load(hpTb + 64, NN, t, ra, rb);
  rd = (t < 64) ? dTb[(size_t)(64 + t) * HH] : 0.f;
  __syncthreads();

  const int NT = NN / 64;
  for (int it = 0; it < NT; ++it) {
    int buf = it & 1;
    // 1. write-late: store tile it+1 into buf^1
    if (it + 1 < NT) {
      tile_store(hp_lds[buf ^ 1], t, ra, rb);
      if (t < 64) d_lds[buf ^ 1][t] = rd;
    }
    // 2. issue-early: load tile it+2 into regs
    if (it + 2 < NT) {
      tile_load(hpTb + (it + 2) * 64, NN, t, ra, rb);
      rd = (t < 64) ? dTb[(size_t)((it + 2) * 64 + t) * HH] : 0.f;
    }
    // 3. compute weight A-fragments in registers + accumulate l
    unsigned long long bw = brow[it];
    unsigned int bsel[2];
    bsel[0] = (unsigned int)(bw >> kb);
    bsel[1] = (unsigned int)(bw >> (32 + kb));
    float4 dv[4];
    dv[0] = *(const float4*)&d_lds[buf][kb];
    dv[1] = *(const float4*)&d_lds[buf][kb + 4];
    dv[2] = *(const float4*)&d_lds[buf][32 + kb];
    dv[3] = *(const float4*)&d_lds[buf][32 + kb + 4];
    union { unsigned int u[4]; s16x8 v; } af[2];
#pragma unroll
    for (int kk = 0; kk < 2; ++kk) {
      const float* dp = (const float*)&dv[kk * 2];
      float w8[8];
#pragma unroll
      for (int c = 0; c < 8; ++c) {
        float x = sreg + dp[c];
        float xl = fmaxf(x, 0.2f * x);
        float e = __builtin_amdgcn_exp2f(xl);
        float val = (bsel[kk] & (1u << c)) ? e : 0.f;
        suml += val;
        w8[c] = val;
      }
#pragma unroll
      for (int p = 0; p < 4; ++p) {
        unsigned int pk;
        asm volatile("v_cvt_pk_bf16_f32 %0, %1, %2"
                     : "=v"(pk) : "v"(w8[2 * p]), "v"(w8[2 * p + 1]));
        af[kk].u[p] = pk;
      }
    }
    // 4. MFMA
#pragma unroll
    for (int kk = 0; kk < 2; ++kk) {
#pragma unroll
      for (int nf = 0; nf < 4; ++nf) {
        s16x8 bv = *tile_read_ptr(hp_lds[buf], nf * 16 + (lane & 15),
                                  kk * 64 + (lane >> 4) * 16);
        acc[nf] = __builtin_amdgcn_mfma_f32_16x16x32_bf16(af[kk].v, bv, acc[nf], 0, 0, 0);
      }
    }
    __syncthreads();
  }
  // l: reduce across the 4 lanes sharing rowi (xor 16, 32)
  suml += __shfl_xor(suml, 16);
  suml += __shfl_xor(suml, 32);
  if (lane < 16) l_lds[wv * 16 + lane] = suml;
  __syncthreads();
  int col = lane & 15, r0 = (lane >> 4) * 4;
#pragma unroll
  for (int reg = 0; reg < 4; ++reg) {
    int m = wv * 16 + r0 + reg;
    float linv = 1.0f / l_lds[m];
    size_t ob = (((size_t)b * HH + h) * NN + i0 + m) * 64 + col;
#pragma unroll
    for (int nf = 0; nf < 4; ++nf)
      outp[ob + nf * 16] = acc[nf][reg] * linv;
  }
}

// ---------------- transpose (b,h,n,o)->(b,n,h*64+o) + elu -> bf16 ----------
__global__ __launch_bounds__(256) void k_trans_elu(
    const float* __restrict__ in, unsigned short* __restrict__ outp) {
  int idx = blockIdx.x * 256 + threadIdx.x;   // over BSZ*HH*NN*64
  int o = idx & 63;
  int rest = idx >> 6;
  int n = rest & (NN - 1);
  int bh = rest >> 11;
  int h = bh & (HH - 1);
  int b = bh >> 3;
  float v = in[idx];
  v = v > 0.f ? v : (__expf(v) - 1.f);
  outp[((size_t)b * NN + n) * K1 + h * 64 + o] = f2b(v);
}

// ---------------- mean over heads → seq[b,n,r,:] ----------------------------
__global__ __launch_bounds__(256) void k_mean(
    const float* __restrict__ in, float* __restrict__ seq, int r) {
  int idx = blockIdx.x * 256 + threadIdx.x;   // over BSZ*NN*64
  int o = idx & 63;
  int rest = idx >> 6;
  int n = rest & (NN - 1);
  int b = rest >> 11;
  float acc = 0.f;
#pragma unroll
  for (int h = 0; h < HH; ++h)
    acc += in[(((size_t)b * HH + h) * NN + n) * 64 + o];
  seq[(((size_t)b * NN + n) * NADJ + r) * 64 + o] = acc * 0.125f;
}

// ---------------- final fusion + log_softmax --------------------------------
__global__ __launch_bounds__(256) void k_fuse(
    const float* __restrict__ fp, const float* __restrict__ seq,
    const float* __restrict__ aw2, const float* __restrict__ am,
    float* __restrict__ outp) {
  __shared__ float w2[64][65];
  __shared__ float amv[64];
  __shared__ float seq_lds[4][NADJ][64];
  int t = threadIdx.x;
#pragma unroll
  for (int q = 0; q < 16; ++q) {
    int e = t + 256 * q;
    w2[e >> 6][e & 63] = aw2[e];
  }
  if (t < 64) amv[t] = am[t];
  int wid = t >> 6, lane = t & 63;
  int bn = blockIdx.x * 4 + wid;               // over BSZ*NN
  float s0 = seq[((size_t)bn * NADJ + 0) * 64 + lane];
  float s1 = seq[((size_t)bn * NADJ + 1) * 64 + lane];
  seq_lds[wid][0][lane] = s0;
  seq_lds[wid][1][lane] = s1;
  __syncthreads();
  float f = fp[(size_t)bn * 64 + lane];
  float q0 = f, q1 = f;
  for (int k = 0; k < 64; ++k) {
    float wv = w2[k][lane];
    q0 += seq_lds[wid][0][k] * wv;
    q1 += seq_lds[wid][1][k] * wv;
  }
  q0 = tanhf(q0); q1 = tanhf(q1);
  float sc0 = q0 * amv[lane], sc1 = q1 * amv[lane];
  for (int off = 32; off; off >>= 1) {
    sc0 += __shfl_xor(sc0, off);
    sc1 += __shfl_xor(sc1, off);
  }
  float mx = fmaxf(sc0, sc1);
  float e0 = __expf(sc0 - mx), e1 = __expf(sc1 - mx);
  float inv = 1.f / (e0 + e1);
  float fu = (e0 * inv) * s0 + (e1 * inv) * s1;
  float m = fu;
  for (int off = 32; off; off >>= 1) m = fmaxf(m, __shfl_xor(m, off));
  float ex = __expf(fu - m);
  float ssum = ex;
  for (int off = 32; off; off >>= 1) ssum += __shfl_xor(ssum, off);
  outp[(size_t)bn * 64 + lane] = fu - m - __logf(ssum);
}

extern "C" void kernel_launch(void* const* d_in, const int* in_sizes, int n_in,
                              void* d_out, int out_size, void* d_ws, size_t ws_size,
                              hipStream_t stream) {
  (void)in_sizes; (void)n_in; (void)out_size; (void)ws_size;
  const float* hg   = (const float*)d_in[0];
  const int*   vert = (const int*)d_in[1];
  const float* lemb = (const float*)d_in[2];
  const float* emb0 = (const float*)d_in[3];
  const float* emb1 = (const float*)d_in[4];
  const float* w_l0 = (const float*)d_in[5];
  const float* as0  = (const float*)d_in[6];
  const float* ad0  = (const float*)d_in[7];
  const float* w_l1 = (const float*)d_in[8];
  const float* as1  = (const float*)d_in[9];
  const float* ad1  = (const float*)d_in[10];
  const float* aw1  = (const float*)d_in[11];
  const float* aw2  = (const float*)d_in[12];
  const float* am   = (const float*)d_in[13];
  float* out = (float*)d_out;

  char* p = (char*)d_ws;
  float* hp             = (float*)p;           p += (size_t)BSZ*HH*NN*64*4;   // 8MB
  float* aout           = (float*)p;           p += (size_t)BSZ*HH*NN*64*4;   // 8MB
  unsigned short* hpT   = (unsigned short*)p;  p += (size_t)BSZ*HH*NN*64*2;   // 4MB
  unsigned short* featB = (unsigned short*)p;  p += (size_t)BSZ*NN*NF*2;      // 1.5MB
  unsigned short* hmidB = (unsigned short*)p;  p += (size_t)BSZ*NN*K1*2;      // 2MB
  unsigned short* wT0   = (unsigned short*)p;  p += (size_t)NADJ*HH*64*NF*2;  // 384KB
  unsigned short* wT1   = (unsigned short*)p;  p += (size_t)NADJ*HH*64*K1*2;  // 1MB
  unsigned short* awT   = (unsigned short*)p;  p += (size_t)64*NF*2;          // 24KB
  float* sT             = (float*)p;           p += (size_t)BSZ*NN*HH*4;      // 128KB
  float* dT             = (float*)p;           p += (size_t)BSZ*NN*HH*4;      // 128KB
  unsigned long long* bits = (unsigned long long*)p; p += (size_t)BSZ*NADJ*NN*(NN/64)*8; // 2MB
  float* seq            = (float*)p;           p += (size_t)BSZ*NN*NADJ*64*4; // 2MB
  float* fproj          = (float*)p;           p += (size_t)BSZ*NN*64*4;      // 1MB

  // one-time prep
  k_build_feat<<<(BSZ*NN*NF)/256, 256, 0, stream>>>(vert, lemb, emb0, emb1, featB);
  k_bits<<<(size_t)BSZ*NADJ*NN*NN/256, 256, 0, stream>>>(hg, bits);
  k_tcast<<<dim3(NF/64, NADJ*HH), 256, 0, stream>>>(w_l0, wT0, NF);
  k_tcast<<<dim3(K1/64, NADJ*HH), 256, 0, stream>>>(w_l1, wT1, K1);
  k_tcast<<<dim3(NF/64, 1), 256, 0, stream>>>(aw1, awT, NF);
  k_gemm_bf16<NF><<<dim3(NN/64, 1, BSZ), 256, 0, stream>>>(featB, awT, fproj, 1);

  for (int r = 0; r < NADJ; ++r) {
    // layer 0
    k_gemm_bf16<NF><<<dim3(NN/64, HH, BSZ), 256, 0, stream>>>(
        featB, wT0 + (size_t)r*HH*64*NF, hp, HH);
    k_tcast<<<dim3(NN/64, BSZ*HH), 256, 0, stream>>>(hp, hpT, NN);
    k_sd<<<BSZ*HH*NN/4, 256, 0, stream>>>(hp, as0 + r*HH*64, ad0 + r*HH*64, sT, dT);
    k_pv<<<dim3(NN/64, HH, BSZ), 256, 0, stream>>>(bits, r, hpT, sT, dT, aout);
    k_trans_elu<<<(BSZ*HH*NN*64)/256, 256, 0, stream>>>(aout, hmidB);
    // layer 1
    k_gemm_bf16<K1><<<dim3(NN/64, HH, BSZ), 256, 0, stream>>>(
        hmidB, wT1 + (size_t)r*HH*64*K1, hp, HH);
    k_tcast<<<dim3(NN/64, BSZ*HH), 256, 0, stream>>>(hp, hpT, NN);
    k_sd<<<BSZ*HH*NN/4, 256, 0, stream>>>(hp, as1 + r*HH*64, ad1 + r*HH*64, sT, dT);
    k_pv<<<dim3(NN/64, HH, BSZ), 256, 0, stream>>>(bits, r, hpT, sT, dT, aout);
    k_mean<<<(BSZ*NN*64)/256, 256, 0, stream>>>(aout, seq, r);
  }
  k_fuse<<<BSZ*NN/4, 256, 0, stream>>>(fproj, seq, aw2, am, out);
}

// Round 4
// 211.083 us; speedup vs baseline: 7.3804x; 1.3718x over previous
//
#include <hip/hip_runtime.h>
#include <hip/hip_bf16.h>

#define BSZ 2
#define NADJ 2
#define NN 2048
#define DE 64
#define HH 8
#define F1 64
#define NF 192   // 3*DE
#define K1 512   // HH*F1
#define LOG2E 1.4426950408889634f

typedef short s16x8 __attribute__((ext_vector_type(8)));
typedef unsigned short u16x8 __attribute__((ext_vector_type(8)));
typedef float f32x4 __attribute__((ext_vector_type(4)));

__device__ __forceinline__ unsigned short f2b(float x) {
  union { float f; unsigned int u; } v; v.f = x;
  unsigned int r = v.u + 0x7fffu + ((v.u >> 16) & 1u);
  return (unsigned short)(r >> 16);
}
__device__ __forceinline__ float b2f(unsigned short u) {
  union { unsigned int u; float f; } v; v.u = ((unsigned int)u) << 16;
  return v.f;
}

// ---- 64x64 bf16 tile staging helpers (XOR-swizzled LDS, 128B rows) ---------
__device__ __forceinline__ void tile_load(const unsigned short* g, int rowstride,
                                          int t, u16x8& a, u16x8& b) {
  int o = t >> 2, j = (t & 3) * 16;
  const unsigned short* p = g + (size_t)o * rowstride + j;
  a = *(const u16x8*)p;
  b = *(const u16x8*)(p + 8);
}
__device__ __forceinline__ void tile_store(unsigned short* lds, int t, u16x8 a, u16x8 b) {
  int o = t >> 2, jb = (t & 3) * 32;
  int swz = (o & 7) << 4;
  char* base = (char*)lds + o * 128;
  *(u16x8*)(base + (jb ^ swz)) = a;
  *(u16x8*)(base + ((jb + 16) ^ swz)) = b;
}
__device__ __forceinline__ const s16x8* tile_read_ptr(const unsigned short* lds,
                                                      int row, int kbyte) {
  return (const s16x8*)((const char*)lds + row * 128 + (kbyte ^ ((row & 7) << 4)));
}

// ---------------- build feat = [emb0[v], emb1[v], local_emb] (bf16) ---------
__global__ __launch_bounds__(256) void k_build_feat(
    const int* __restrict__ vert, const float* __restrict__ lemb,
    const float* __restrict__ emb0, const float* __restrict__ emb1,
    unsigned short* __restrict__ featB) {
  int idx = blockIdx.x * 256 + threadIdx.x;          // over BSZ*NN*NF
  int f = idx % NF;
  int bn = idx / NF;
  int v = vert[bn];
  float val;
  if (f < 64)       val = emb0[v * 64 + f];
  else if (f < 128) val = emb1[v * 64 + (f - 64)];
  else              val = lemb[bn * 64 + (f - 128)];
  featB[idx] = f2b(val);
}

// ---------------- adjacency ballot bitmask ----------------------------------
__global__ __launch_bounds__(256) void k_bits(
    const float* __restrict__ hg, unsigned long long* __restrict__ bits) {
  size_t idx = (size_t)blockIdx.x * 256 + threadIdx.x;   // over BSZ*NADJ*NN*NN
  float a = hg[idx];
  unsigned long long m = __ballot(a > 0.f);
  if ((threadIdx.x & 63) == 0) bits[idx >> 6] = m;
}

// ---------------- transpose-cast src[plane][R][64] f32 -> dst[plane][64][R] bf16
__global__ __launch_bounds__(256) void k_tcast(
    const float* __restrict__ src, unsigned short* __restrict__ dst, int R) {
  __shared__ unsigned short tr[64][72];
  int k0 = blockIdx.x * 64;
  int plane = blockIdx.y;
  const float* s = src + (size_t)plane * R * 64;
  unsigned short* d = dst + (size_t)plane * 64 * R;
  int t = threadIdx.x;
#pragma unroll
  for (int q = 0; q < 4; ++q) {
    int e = q * 256 + t;
    int kr = e >> 4, oc = (e & 15) * 4;
    float4 v = *(const float4*)&s[(size_t)(k0 + kr) * 64 + oc];
    tr[oc + 0][kr] = f2b(v.x);
    tr[oc + 1][kr] = f2b(v.y);
    tr[oc + 2][kr] = f2b(v.z);
    tr[oc + 3][kr] = f2b(v.w);
  }
  __syncthreads();
#pragma unroll
  for (int q = 0; q < 2; ++q) {
    int e = q * 256 + t;
    int o = e >> 3, j8 = (e & 7) * 8;
    *(u16x8*)&d[(size_t)o * R + k0 + j8] = *(const u16x8*)&tr[o][j8];
  }
}

// ---------------- plain bf16 MFMA GEMM (for fproj): out fp32 ---------------
template <int K>
__global__ __launch_bounds__(256) void k_gemm_bf16(
    const unsigned short* __restrict__ A, const unsigned short* __restrict__ Bw,
    float* __restrict__ outp, int nheads) {
  __shared__ unsigned short a_lds[2][64 * 64];
  __shared__ unsigned short b_lds[2][64 * 64];
  int tile = blockIdx.x, h = blockIdx.y, b = blockIdx.z;
  int t = threadIdx.x, lane = t & 63, wv = t >> 6;
  const unsigned short* Ab = A + ((size_t)b * NN + tile * 64) * K;
  const unsigned short* Bb = Bw + (size_t)h * 64 * K;
  const int NT = K / 64;
  u16x8 a0, a1, b0, b1;
  tile_load(Ab, K, t, a0, a1);
  tile_load(Bb, K, t, b0, b1);
  tile_store(a_lds[0], t, a0, a1);
  tile_store(b_lds[0], t, b0, b1);
  if (NT > 1) { tile_load(Ab + 64, K, t, a0, a1); tile_load(Bb + 64, K, t, b0, b1); }
  __syncthreads();
  f32x4 acc[4] = {};
  int rowA = wv * 16 + (lane & 15);
  int rowB0 = lane & 15;
  int kb2 = (lane >> 4) * 16;
  for (int it = 0; it < NT; ++it) {
    int buf = it & 1;
    if (it + 1 < NT) {
      tile_store(a_lds[buf ^ 1], t, a0, a1);
      tile_store(b_lds[buf ^ 1], t, b0, b1);
    }
    if (it + 2 < NT) {
      tile_load(Ab + (it + 2) * 64, K, t, a0, a1);
      tile_load(Bb + (it + 2) * 64, K, t, b0, b1);
    }
#pragma unroll
    for (int kk = 0; kk < 2; ++kk) {
      s16x8 av = *tile_read_ptr(a_lds[buf], rowA, kk * 64 + kb2);
#pragma unroll
      for (int nf = 0; nf < 4; ++nf) {
        s16x8 bv = *tile_read_ptr(b_lds[buf], nf * 16 + rowB0, kk * 64 + kb2);
        acc[nf] = __builtin_amdgcn_mfma_f32_16x16x32_bf16(av, bv, acc[nf], 0, 0, 0);
      }
    }
    __syncthreads();
  }
  int col = lane & 15, r0 = (lane >> 4) * 4;
  size_t ob = (((size_t)b * nheads + h) * NN + tile * 64 + wv * 16 + r0) * 64 + col;
#pragma unroll
  for (int reg = 0; reg < 4; ++reg) {
#pragma unroll
    for (int nf = 0; nf < 4; ++nf)
      outp[ob + (size_t)reg * 64 + nf * 16] = acc[nf][reg];
  }
}

// ---------------- fused GEMM: hpT bf16 (transposed) + s,d in epilogue -------
// A bf16 [b][n][K]; Bw = W^T bf16 [h][o][K]. No fp32 hp output.
template <int K>
__global__ __launch_bounds__(256) void k_gemm_fused(
    const unsigned short* __restrict__ A, const unsigned short* __restrict__ Bw,
    const float* __restrict__ a_src, const float* __restrict__ a_dst,
    unsigned short* __restrict__ hpT, float* __restrict__ sT, float* __restrict__ dT) {
  __shared__ unsigned short a_lds[2][64 * 64];
  __shared__ unsigned short b_lds[2][64 * 64];
  int tile = blockIdx.x, h = blockIdx.y, b = blockIdx.z;
  int t = threadIdx.x, lane = t & 63, wv = t >> 6;
  const unsigned short* Ab = A + ((size_t)b * NN + tile * 64) * K;
  const unsigned short* Bb = Bw + (size_t)h * 64 * K;
  const int NT = K / 64;
  u16x8 a0, a1, b0, b1;
  tile_load(Ab, K, t, a0, a1);
  tile_load(Bb, K, t, b0, b1);
  tile_store(a_lds[0], t, a0, a1);
  tile_store(b_lds[0], t, b0, b1);
  if (NT > 1) { tile_load(Ab + 64, K, t, a0, a1); tile_load(Bb + 64, K, t, b0, b1); }
  __syncthreads();
  f32x4 acc[4] = {};
  int rowA = wv * 16 + (lane & 15);
  int rowB0 = lane & 15;
  int kb2 = (lane >> 4) * 16;
  for (int it = 0; it < NT; ++it) {
    int buf = it & 1;
    if (it + 1 < NT) {
      tile_store(a_lds[buf ^ 1], t, a0, a1);
      tile_store(b_lds[buf ^ 1], t, b0, b1);
    }
    if (it + 2 < NT) {
      tile_load(Ab + (it + 2) * 64, K, t, a0, a1);
      tile_load(Bb + (it + 2) * 64, K, t, b0, b1);
    }
#pragma unroll
    for (int kk = 0; kk < 2; ++kk) {
      s16x8 av = *tile_read_ptr(a_lds[buf], rowA, kk * 64 + kb2);
#pragma unroll
      for (int nf = 0; nf < 4; ++nf) {
        s16x8 bv = *tile_read_ptr(b_lds[buf], nf * 16 + rowB0, kk * 64 + kb2);
        acc[nf] = __builtin_amdgcn_mfma_f32_16x16x32_bf16(av, bv, acc[nf], 0, 0, 0);
      }
    }
    __syncthreads();
  }
  // ---- epilogue 1: s,d = sum_o tanh(hp)*a (fast tanh), scaled by LOG2E ----
  float sp[4] = {}, dp[4] = {};
#pragma unroll
  for (int nf = 0; nf < 4; ++nf) {
    int c = nf * 16 + (lane & 15);
    float as = a_src[h * 64 + c], ad = a_dst[h * 64 + c];
#pragma unroll
    for (int reg = 0; reg < 4; ++reg) {
      float x = acc[nf][reg];
      x = fminf(fmaxf(x, -30.f), 30.f);
      float e2 = __builtin_amdgcn_exp2f(x * (2.f * LOG2E));
      float th = (e2 - 1.f) * __builtin_amdgcn_rcpf(e2 + 1.f);
      sp[reg] += th * as;
      dp[reg] += th * ad;
    }
  }
#pragma unroll
  for (int reg = 0; reg < 4; ++reg) {
#pragma unroll
    for (int off = 8; off; off >>= 1) {
      sp[reg] += __shfl_xor(sp[reg], off);
      dp[reg] += __shfl_xor(dp[reg], off);
    }
  }
  if ((lane & 15) == 0) {
#pragma unroll
    for (int reg = 0; reg < 4; ++reg) {
      int m = tile * 64 + wv * 16 + (lane >> 4) * 4 + reg;
      sT[((size_t)b * NN + m) * HH + h] = sp[reg] * LOG2E;
      dT[((size_t)b * NN + m) * HH + h] = dp[reg] * LOG2E;
    }
  }
  // ---- epilogue 2: transpose-cast to hpT via LDS bounce (stride 76) -------
  unsigned short* tr = a_lds[0];
#pragma unroll
  for (int nf = 0; nf < 4; ++nf) {
    int c = nf * 16 + (lane & 15);
#pragma unroll
    for (int reg = 0; reg < 4; ++reg) {
      int m = wv * 16 + (lane >> 4) * 4 + reg;
      tr[c * 76 + m] = f2b(acc[nf][reg]);
    }
  }
  __syncthreads();
  unsigned short* dst = hpT + (size_t)(b * HH + h) * 64 * NN + tile * 64;
#pragma unroll
  for (int q = 0; q < 2; ++q) {
    int e = q * 256 + t;
    int o = e >> 3, j8 = (e & 7) * 8;
    u16x8 v;
#pragma unroll
    for (int z = 0; z < 8; ++z) v[z] = tr[o * 76 + j8 + z];
    *(u16x8*)&dst[(size_t)o * NN + j8] = v;
  }
}

// ---------------- PV (MFMA, BK=128, l via ones-column MFMA) -----------------
// MODE 0: write aoutB bf16 [b,h,n,o].  MODE 1: write hmidB bf16 [b,n,h*64+o] with ELU.
template <int MODE>
__global__ __launch_bounds__(256) void k_pv(
    const unsigned long long* __restrict__ bits, int r,
    const unsigned short* __restrict__ hpT,
    const float* __restrict__ sT, const float* __restrict__ dT,
    unsigned short* __restrict__ outB) {
  __shared__ unsigned short hp_lds[2][2][64 * 64];
  __shared__ float d_lds[2][128];
  int i0 = blockIdx.x * 64, h = blockIdx.y, b = blockIdx.z;
  int t = threadIdx.x, lane = t & 63, wv = t >> 6;
  int rowi = wv * 16 + (lane & 15);
  int kb = (lane >> 4) * 8;
  float sreg = sT[((size_t)b * NN + i0 + rowi) * HH + h];
  const unsigned long long* brow =
      bits + ((size_t)(b * NADJ + r) * NN + i0 + rowi) * (NN / 64);
  const unsigned short* hpTb = hpT + (size_t)(b * HH + h) * 64 * NN;
  const float* dTb = dT + (size_t)b * NN * HH + h;
  f32x4 acc[4] = {};
  f32x4 accl = {};
  const short ONE = (short)0x3F80;
  const s16x8 ones = {ONE, ONE, ONE, ONE, ONE, ONE, ONE, ONE};

  u16x8 ra[2], rb[2];
  float rd;
  // iter 0 -> LDS buf0
  tile_load(hpTb, NN, t, ra[0], rb[0]);
  tile_load(hpTb + 64, NN, t, ra[1], rb[1]);
  rd = (t < 128) ? dTb[(size_t)t * HH] : 0.f;
  tile_store(hp_lds[0][0], t, ra[0], rb[0]);
  tile_store(hp_lds[0][1], t, ra[1], rb[1]);
  if (t < 128) d_lds[0][t] = rd;
  // iter 1 -> regs
  tile_load(hpTb + 128, NN, t, ra[0], rb[0]);
  tile_load(hpTb + 192, NN, t, ra[1], rb[1]);
  rd = (t < 128) ? dTb[(size_t)(128 + t) * HH] : 0.f;
  unsigned long long bw0 = brow[0], bw1 = brow[1];
  __syncthreads();

  const int NT = NN / 128;   // 16
  for (int it = 0; it < NT; ++it) {
    int buf = it & 1;
    if (it + 1 < NT) {
      tile_store(hp_lds[buf ^ 1][0], t, ra[0], rb[0]);
      tile_store(hp_lds[buf ^ 1][1], t, ra[1], rb[1]);
      if (t < 128) d_lds[buf ^ 1][t] = rd;
    }
    if (it + 2 < NT) {
      tile_load(hpTb + (it + 2) * 128, NN, t, ra[0], rb[0]);
      tile_load(hpTb + (it + 2) * 128 + 64, NN, t, ra[1], rb[1]);
      rd = (t < 128) ? dTb[(size_t)((it + 2) * 128 + t) * HH] : 0.f;
    }
    unsigned long long bwn0 = 0, bwn1 = 0;
    if (it + 1 < NT) { bwn0 = brow[2 * (it + 1)]; bwn1 = brow[2 * (it + 1) + 1]; }
#pragma unroll
    for (int jt = 0; jt < 2; ++jt) {
      unsigned long long bw = jt ? bw1 : bw0;
      unsigned int bsel[2];
      bsel[0] = (unsigned int)(bw >> kb);
      bsel[1] = (unsigned int)(bw >> (32 + kb));
      union { unsigned int u[4]; s16x8 v; } af[2];
#pragma unroll
      for (int kk = 0; kk < 2; ++kk) {
        float w8[8];
#pragma unroll
        for (int c = 0; c < 8; ++c) {
          float dv = d_lds[buf][jt * 64 + kk * 32 + kb + c];
          float x = sreg + dv;
          float xl = fmaxf(x, 0.2f * x);
          float e = __builtin_amdgcn_exp2f(xl);
          w8[c] = (bsel[kk] & (1u << c)) ? e : 0.f;
        }
#pragma unroll
        for (int p = 0; p < 4; ++p) {
          unsigned int pk;
          asm volatile("v_cvt_pk_bf16_f32 %0, %1, %2"
                       : "=v"(pk) : "v"(w8[2 * p]), "v"(w8[2 * p + 1]));
          af[kk].u[p] = pk;
        }
      }
#pragma unroll
      for (int kk = 0; kk < 2; ++kk) {
#pragma unroll
        for (int nf = 0; nf < 4; ++nf) {
          s16x8 bv = *tile_read_ptr(hp_lds[buf][jt], nf * 16 + (lane & 15),
                                    kk * 64 + (lane >> 4) * 16);
          acc[nf] = __builtin_amdgcn_mfma_f32_16x16x32_bf16(af[kk].v, bv, acc[nf], 0, 0, 0);
        }
        accl = __builtin_amdgcn_mfma_f32_16x16x32_bf16(af[kk].v, ones, accl, 0, 0, 0);
      }
    }
    bw0 = bwn0; bw1 = bwn1;
    __syncthreads();
  }
  // ---- epilogue: D layout col=lane&15, row=(lane>>4)*4+reg ----
  int col = lane & 15, r0g = (lane >> 4) * 4;
#pragma unroll
  for (int reg = 0; reg < 4; ++reg) {
    int m = wv * 16 + r0g + reg;
    float linv = 1.0f / accl[reg];
    if (MODE == 0) {
      size_t ob = (((size_t)b * HH + h) * NN + i0 + m) * 64 + col;
#pragma unroll
      for (int nf = 0; nf < 4; ++nf)
        outB[ob + nf * 16] = f2b(acc[nf][reg] * linv);
    } else {
      size_t ob = ((size_t)b * NN + i0 + m) * K1 + h * 64 + col;
#pragma unroll
      for (int nf = 0; nf < 4; ++nf) {
        float v = acc[nf][reg] * linv;
        v = v > 0.f ? v : (__builtin_amdgcn_exp2f(v * LOG2E) - 1.f);
        outB[ob + nf * 16] = f2b(v);
      }
    }
  }
}

// ---------------- mean over heads → seq[b,n,r,:] (bf16 in) ------------------
__global__ __launch_bounds__(256) void k_mean(
    const unsigned short* __restrict__ in, float* __restrict__ seq, int r) {
  int idx = blockIdx.x * 256 + threadIdx.x;   // over BSZ*NN*8 (8 o's each)
  int o8 = (idx & 7) * 8;
  int n = (idx >> 3) & (NN - 1);
  int b = idx >> 14;
  float acc[8] = {};
#pragma unroll
  for (int h = 0; h < HH; ++h) {
    u16x8 v = *(const u16x8*)&in[(((size_t)b * HH + h) * NN + n) * 64 + o8];
#pragma unroll
    for (int z = 0; z < 8; ++z) acc[z] += b2f((unsigned short)v[z]);
  }
  float* dst = &seq[(((size_t)b * NN + n) * NADJ + r) * 64 + o8];
#pragma unroll
  for (int z = 0; z < 8; ++z) dst[z] = acc[z] * 0.125f;
}

// ---------------- final fusion + log_softmax --------------------------------
__global__ __launch_bounds__(256) void k_fuse(
    const float* __restrict__ fp, const float* __restrict__ seq,
    const float* __restrict__ aw2, const float* __restrict__ am,
    float* __restrict__ outp) {
  __shared__ float w2[64][65];
  __shared__ float amv[64];
  __shared__ float seq_lds[4][NADJ][64];
  int t = threadIdx.x;
#pragma unroll
  for (int q = 0; q < 16; ++q) {
    int e = t + 256 * q;
    w2[e >> 6][e & 63] = aw2[e];
  }
  if (t < 64) amv[t] = am[t];
  int wid = t >> 6, lane = t & 63;
  int bn = blockIdx.x * 4 + wid;               // over BSZ*NN
  float s0 = seq[((size_t)bn * NADJ + 0) * 64 + lane];
  float s1 = seq[((size_t)bn * NADJ + 1) * 64 + lane];
  seq_lds[wid][0][lane] = s0;
  seq_lds[wid][1][lane] = s1;
  __syncthreads();
  float f = fp[(size_t)bn * 64 + lane];
  float q0 = f, q1 = f;
  for (int k = 0; k < 64; ++k) {
    float wv = w2[k][lane];
    q0 += seq_lds[wid][0][k] * wv;
    q1 += seq_lds[wid][1][k] * wv;
  }
  q0 = tanhf(q0); q1 = tanhf(q1);
  float sc0 = q0 * amv[lane], sc1 = q1 * amv[lane];
  for (int off = 32; off; off >>= 1) {
    sc0 += __shfl_xor(sc0, off);
    sc1 += __shfl_xor(sc1, off);
  }
  float mx = fmaxf(sc0, sc1);
  float e0 = __expf(sc0 - mx), e1 = __expf(sc1 - mx);
  float inv = 1.f / (e0 + e1);
  float fu = (e0 * inv) * s0 + (e1 * inv) * s1;
  float m = fu;
  for (int off = 32; off; off >>= 1) m = fmaxf(m, __shfl_xor(m, off));
  float ex = __expf(fu - m);
  float ssum = ex;
  for (int off = 32; off; off >>= 1) ssum += __shfl_xor(ssum, off);
  outp[(size_t)bn * 64 + lane] = fu - m - __logf(ssum);
}

extern "C" void kernel_launch(void* const* d_in, const int* in_sizes, int n_in,
                              void* d_out, int out_size, void* d_ws, size_t ws_size,
                              hipStream_t stream) {
  (void)in_sizes; (void)n_in; (void)out_size; (void)ws_size;
  const float* hg   = (const float*)d_in[0];
  const int*   vert = (const int*)d_in[1];
  const float* lemb = (const float*)d_in[2];
  const float* emb0 = (const float*)d_in[3];
  const float* emb1 = (const float*)d_in[4];
  const float* w_l0 = (const float*)d_in[5];
  const float* as0  = (const float*)d_in[6];
  const float* ad0  = (const float*)d_in[7];
  const float* w_l1 = (const float*)d_in[8];
  const float* as1  = (const float*)d_in[9];
  const float* ad1  = (const float*)d_in[10];
  const float* aw1  = (const float*)d_in[11];
  const float* aw2  = (const float*)d_in[12];
  const float* am   = (const float*)d_in[13];
  float* out = (float*)d_out;

  char* p = (char*)d_ws;
  unsigned short* hpT   = (unsigned short*)p;  p += (size_t)BSZ*HH*NN*64*2;   // 4MB
  unsigned short* aoutB = (unsigned short*)p;  p += (size_t)BSZ*HH*NN*64*2;   // 4MB
  unsigned short* featB = (unsigned short*)p;  p += (size_t)BSZ*NN*NF*2;      // 1.5MB
  unsigned short* hmidB = (unsigned short*)p;  p += (size_t)BSZ*NN*K1*2;      // 4MB
  unsigned short* wT0   = (unsigned short*)p;  p += (size_t)NADJ*HH*64*NF*2;
  unsigned short* wT1   = (unsigned short*)p;  p += (size_t)NADJ*HH*64*K1*2;
  unsigned short* awT   = (unsigned short*)p;  p += (size_t)64*NF*2;
  float* sT             = (float*)p;           p += (size_t)BSZ*NN*HH*4;
  float* dT             = (float*)p;           p += (size_t)BSZ*NN*HH*4;
  unsigned long long* bits = (unsigned long long*)p; p += (size_t)BSZ*NADJ*NN*(NN/64)*8;
  float* seq            = (float*)p;           p += (size_t)BSZ*NN*NADJ*64*4;
  float* fproj          = (float*)p;           p += (size_t)BSZ*NN*64*4;

  // one-time prep
  k_build_feat<<<(BSZ*NN*NF)/256, 256, 0, stream>>>(vert, lemb, emb0, emb1, featB);
  k_bits<<<(size_t)BSZ*NADJ*NN*NN/256, 256, 0, stream>>>(hg, bits);
  k_tcast<<<dim3(NF/64, NADJ*HH), 256, 0, stream>>>(w_l0, wT0, NF);
  k_tcast<<<dim3(K1/64, NADJ*HH), 256, 0, stream>>>(w_l1, wT1, K1);
  k_tcast<<<dim3(NF/64, 1), 256, 0, stream>>>(aw1, awT, NF);
  k_gemm_bf16<NF><<<dim3(NN/64, 1, BSZ), 256, 0, stream>>>(featB, awT, fproj, 1);

  for (int r = 0; r < NADJ; ++r) {
    // layer 0
    k_gemm_fused<NF><<<dim3(NN/64, HH, BSZ), 256, 0, stream>>>(
        featB, wT0 + (size_t)r*HH*64*NF, as0 + r*HH*64, ad0 + r*HH*64, hpT, sT, dT);
    k_pv<1><<<dim3(NN/64, HH, BSZ), 256, 0, stream>>>(bits, r, hpT, sT, dT, hmidB);
    // layer 1
    k_gemm_fused<K1><<<dim3(NN/64, HH, BSZ), 256, 0, stream>>>(
        hmidB, wT1 + (size_t)r*HH*64*K1, as1 + r*HH*64, ad1 + r*HH*64, hpT, sT, dT);
    k_pv<0><<<dim3(NN/64, HH, BSZ), 256, 0, stream>>>(bits, r, hpT, sT, dT, aoutB);
    k_mean<<<(BSZ*NN*8)/256, 256, 0, stream>>>(aoutB, seq, r);
  }
  k_fuse<<<BSZ*NN/4, 256, 0, stream>>>(fproj, seq, aw2, am, out);
}

// Round 5
// 199.831 us; speedup vs baseline: 7.7959x; 1.0563x over previous
//
#include <hip/hip_runtime.h>
#include <hip/hip_bf16.h>

#define BSZ 2
#define NADJ 2
#define NN 2048
#define DE 64
#define HH 8
#define F1 64
#define NF 192   // 3*DE
#define K1 512   // HH*F1
#define LOG2E 1.4426950408889634f

typedef short s16x8 __attribute__((ext_vector_type(8)));
typedef unsigned short u16x8 __attribute__((ext_vector_type(8)));
typedef float f32x4 __attribute__((ext_vector_type(4)));

__device__ __forceinline__ unsigned short f2b(float x) {
  union { float f; unsigned int u; } v; v.f = x;
  unsigned int r = v.u + 0x7fffu + ((v.u >> 16) & 1u);
  return (unsigned short)(r >> 16);
}
__device__ __forceinline__ float b2f(unsigned short u) {
  union { unsigned int u; float f; } v; v.u = ((unsigned int)u) << 16;
  return v.f;
}

// ---- 64x64 bf16 tile staging helpers (XOR-swizzled LDS, 128B rows) ---------
__device__ __forceinline__ void tile_load(const unsigned short* g, int rowstride,
                                          int t, u16x8& a, u16x8& b) {
  int o = t >> 2, j = (t & 3) * 16;
  const unsigned short* p = g + (size_t)o * rowstride + j;
  a = *(const u16x8*)p;
  b = *(const u16x8*)(p + 8);
}
__device__ __forceinline__ void tile_store(unsigned short* lds, int t, u16x8 a, u16x8 b) {
  int o = t >> 2, jb = (t & 3) * 32;
  int swz = (o & 7) << 4;
  char* base = (char*)lds + o * 128;
  *(u16x8*)(base + (jb ^ swz)) = a;
  *(u16x8*)(base + ((jb + 16) ^ swz)) = b;
}
__device__ __forceinline__ const s16x8* tile_read_ptr(const unsigned short* lds,
                                                      int row, int kbyte) {
  return (const s16x8*)((const char*)lds + row * 128 + (kbyte ^ ((row & 7) << 4)));
}

// ---------------- build feat = [emb0[v], emb1[v], local_emb] (bf16) ---------
__global__ __launch_bounds__(256) void k_build_feat(
    const int* __restrict__ vert, const float* __restrict__ lemb,
    const float* __restrict__ emb0, const float* __restrict__ emb1,
    unsigned short* __restrict__ featB) {
  int idx = blockIdx.x * 256 + threadIdx.x;          // over BSZ*NN*NF
  int f = idx % NF;
  int bn = idx / NF;
  int v = vert[bn];
  float val;
  if (f < 64)       val = emb0[v * 64 + f];
  else if (f < 128) val = emb1[v * 64 + (f - 64)];
  else              val = lemb[bn * 64 + (f - 128)];
  featB[idx] = f2b(val);
}

// ---------------- adjacency ballot bitmask ----------------------------------
__global__ __launch_bounds__(256) void k_bits(
    const float* __restrict__ hg, unsigned long long* __restrict__ bits) {
  size_t idx = (size_t)blockIdx.x * 256 + threadIdx.x;   // over BSZ*NADJ*NN*NN
  float a = hg[idx];
  unsigned long long m = __ballot(a > 0.f);
  if ((threadIdx.x & 63) == 0) bits[idx >> 6] = m;
}

// ---------------- transpose-cast src[plane][R][64] f32 -> dst[plane][64][R] bf16
__global__ __launch_bounds__(256) void k_tcast(
    const float* __restrict__ src, unsigned short* __restrict__ dst, int R) {
  __shared__ unsigned short tr[64][72];
  int k0 = blockIdx.x * 64;
  int plane = blockIdx.y;
  const float* s = src + (size_t)plane * R * 64;
  unsigned short* d = dst + (size_t)plane * 64 * R;
  int t = threadIdx.x;
#pragma unroll
  for (int q = 0; q < 4; ++q) {
    int e = q * 256 + t;
    int kr = e >> 4, oc = (e & 15) * 4;
    float4 v = *(const float4*)&s[(size_t)(k0 + kr) * 64 + oc];
    tr[oc + 0][kr] = f2b(v.x);
    tr[oc + 1][kr] = f2b(v.y);
    tr[oc + 2][kr] = f2b(v.z);
    tr[oc + 3][kr] = f2b(v.w);
  }
  __syncthreads();
#pragma unroll
  for (int q = 0; q < 2; ++q) {
    int e = q * 256 + t;
    int o = e >> 3, j8 = (e & 7) * 8;
    *(u16x8*)&d[(size_t)o * R + k0 + j8] = *(const u16x8*)&tr[o][j8];
  }
}

// ---------------- fused GEMM (256t, K=NF): hpT bf16 + s,d in epilogue -------
template <int K>
__global__ __launch_bounds__(256) void k_gemm_fused(
    const unsigned short* __restrict__ A, const unsigned short* __restrict__ Bw,
    const float* __restrict__ a_src, const float* __restrict__ a_dst,
    unsigned short* __restrict__ hpT, float* __restrict__ sT, float* __restrict__ dT) {
  __shared__ unsigned short a_lds[2][64 * 64];
  __shared__ unsigned short b_lds[2][64 * 64];
  int tile = blockIdx.x, h = blockIdx.y, b = blockIdx.z;
  int t = threadIdx.x, lane = t & 63, wv = t >> 6;
  const unsigned short* Ab = A + ((size_t)b * NN + tile * 64) * K;
  const unsigned short* Bb = Bw + (size_t)h * 64 * K;
  const int NT = K / 64;
  u16x8 a0, a1, b0, b1;
  tile_load(Ab, K, t, a0, a1);
  tile_load(Bb, K, t, b0, b1);
  tile_store(a_lds[0], t, a0, a1);
  tile_store(b_lds[0], t, b0, b1);
  if (NT > 1) { tile_load(Ab + 64, K, t, a0, a1); tile_load(Bb + 64, K, t, b0, b1); }
  __syncthreads();
  f32x4 acc[4] = {};
  int rowA = wv * 16 + (lane & 15);
  int rowB0 = lane & 15;
  int kb2 = (lane >> 4) * 16;
  for (int it = 0; it < NT; ++it) {
    int buf = it & 1;
    if (it + 1 < NT) {
      tile_store(a_lds[buf ^ 1], t, a0, a1);
      tile_store(b_lds[buf ^ 1], t, b0, b1);
    }
    if (it + 2 < NT) {
      tile_load(Ab + (it + 2) * 64, K, t, a0, a1);
      tile_load(Bb + (it + 2) * 64, K, t, b0, b1);
    }
#pragma unroll
    for (int kk = 0; kk < 2; ++kk) {
      s16x8 av = *tile_read_ptr(a_lds[buf], rowA, kk * 64 + kb2);
#pragma unroll
      for (int nf = 0; nf < 4; ++nf) {
        s16x8 bv = *tile_read_ptr(b_lds[buf], nf * 16 + rowB0, kk * 64 + kb2);
        acc[nf] = __builtin_amdgcn_mfma_f32_16x16x32_bf16(av, bv, acc[nf], 0, 0, 0);
      }
    }
    __syncthreads();
  }
  // ---- epilogue 1: s,d ----
  float sp[4] = {}, dp[4] = {};
#pragma unroll
  for (int nf = 0; nf < 4; ++nf) {
    int c = nf * 16 + (lane & 15);
    float as = a_src[h * 64 + c], ad = a_dst[h * 64 + c];
#pragma unroll
    for (int reg = 0; reg < 4; ++reg) {
      float x = acc[nf][reg];
      x = fminf(fmaxf(x, -30.f), 30.f);
      float e2 = __builtin_amdgcn_exp2f(x * (2.f * LOG2E));
      float th = (e2 - 1.f) * __builtin_amdgcn_rcpf(e2 + 1.f);
      sp[reg] += th * as;
      dp[reg] += th * ad;
    }
  }
#pragma unroll
  for (int reg = 0; reg < 4; ++reg) {
#pragma unroll
    for (int off = 8; off; off >>= 1) {
      sp[reg] += __shfl_xor(sp[reg], off);
      dp[reg] += __shfl_xor(dp[reg], off);
    }
  }
  if ((lane & 15) == 0) {
#pragma unroll
    for (int reg = 0; reg < 4; ++reg) {
      int m = tile * 64 + wv * 16 + (lane >> 4) * 4 + reg;
      sT[((size_t)b * NN + m) * HH + h] = sp[reg] * LOG2E;
      dT[((size_t)b * NN + m) * HH + h] = dp[reg] * LOG2E;
    }
  }
  // ---- epilogue 2: transpose-cast to hpT via LDS bounce -------------------
  unsigned short* tr = a_lds[0];
#pragma unroll
  for (int nf = 0; nf < 4; ++nf) {
    int c = nf * 16 + (lane & 15);
#pragma unroll
    for (int reg = 0; reg < 4; ++reg) {
      int m = wv * 16 + (lane >> 4) * 4 + reg;
      tr[c * 76 + m] = f2b(acc[nf][reg]);
    }
  }
  __syncthreads();
  unsigned short* dst = hpT + (size_t)(b * HH + h) * 64 * NN + tile * 64;
#pragma unroll
  for (int q = 0; q < 2; ++q) {
    int e = q * 256 + t;
    int o = e >> 3, j8 = (e & 7) * 8;
    u16x8 v;
#pragma unroll
    for (int z = 0; z < 8; ++z) v[z] = tr[o * 76 + j8 + z];
    *(u16x8*)&dst[(size_t)o * NN + j8] = v;
  }
}

// ---------------- fused GEMM K=512, 512 threads, K-split across wave-quads --
__global__ __launch_bounds__(512) void k_gemm_fused_ks(
    const unsigned short* __restrict__ A, const unsigned short* __restrict__ Bw,
    const float* __restrict__ a_src, const float* __restrict__ a_dst,
    unsigned short* __restrict__ hpT, float* __restrict__ sT, float* __restrict__ dT) {
  __shared__ unsigned short a_lds[2][2][64 * 64];   // [group][dbuf]
  __shared__ unsigned short b_lds[2][2][64 * 64];
  const int K = K1;
  int tile = blockIdx.x, h = blockIdx.y, b = blockIdx.z;
  int t = threadIdx.x, lane = t & 63;
  int wid = t >> 6, g = wid >> 2, wv = wid & 3;
  int tg = t & 255;
  const unsigned short* Ab = A + ((size_t)b * NN + tile * 64) * K + g * 256;
  const unsigned short* Bb = Bw + (size_t)h * 64 * K + g * 256;
  const int NT = 4;
  u16x8 a0, a1, b0, b1;
  tile_load(Ab, K, tg, a0, a1);
  tile_load(Bb, K, tg, b0, b1);
  tile_store(a_lds[g][0], tg, a0, a1);
  tile_store(b_lds[g][0], tg, b0, b1);
  tile_load(Ab + 64, K, tg, a0, a1);
  tile_load(Bb + 64, K, tg, b0, b1);
  __syncthreads();
  f32x4 acc[4] = {};
  int rowA = wv * 16 + (lane & 15);
  int rowB0 = lane & 15;
  int kb2 = (lane >> 4) * 16;
  for (int it = 0; it < NT; ++it) {
    int buf = it & 1;
    if (it + 1 < NT) {
      tile_store(a_lds[g][buf ^ 1], tg, a0, a1);
      tile_store(b_lds[g][buf ^ 1], tg, b0, b1);
    }
    if (it + 2 < NT) {
      tile_load(Ab + (it + 2) * 64, K, tg, a0, a1);
      tile_load(Bb + (it + 2) * 64, K, tg, b0, b1);
    }
#pragma unroll
    for (int kk = 0; kk < 2; ++kk) {
      s16x8 av = *tile_read_ptr(a_lds[g][buf], rowA, kk * 64 + kb2);
#pragma unroll
      for (int nf = 0; nf < 4; ++nf) {
        s16x8 bv = *tile_read_ptr(b_lds[g][buf], nf * 16 + rowB0, kk * 64 + kb2);
        acc[nf] = __builtin_amdgcn_mfma_f32_16x16x32_bf16(av, bv, acc[nf], 0, 0, 0);
      }
    }
    __syncthreads();
  }
  // ---- combine partials: group 1 -> LDS, group 0 adds ----------------------
  float* comb = (float*)&a_lds[0][0][0];   // 16KB
  if (g == 1) {
    float* dst = comb + ((wv * 64 + lane) * 16);
#pragma unroll
    for (int nf = 0; nf < 4; ++nf)
#pragma unroll
      for (int reg = 0; reg < 4; ++reg) dst[nf * 4 + reg] = acc[nf][reg];
  }
  __syncthreads();
  if (g == 0) {
    const float* srcp = comb + ((wv * 64 + lane) * 16);
#pragma unroll
    for (int nf = 0; nf < 4; ++nf)
#pragma unroll
      for (int reg = 0; reg < 4; ++reg) acc[nf][reg] += srcp[nf * 4 + reg];
    // epilogue 1: s,d
    float sp[4] = {}, dp[4] = {};
#pragma unroll
    for (int nf = 0; nf < 4; ++nf) {
      int c = nf * 16 + (lane & 15);
      float as = a_src[h * 64 + c], ad = a_dst[h * 64 + c];
#pragma unroll
      for (int reg = 0; reg < 4; ++reg) {
        float x = acc[nf][reg];
        x = fminf(fmaxf(x, -30.f), 30.f);
        float e2 = __builtin_amdgcn_exp2f(x * (2.f * LOG2E));
        float th = (e2 - 1.f) * __builtin_amdgcn_rcpf(e2 + 1.f);
        sp[reg] += th * as;
        dp[reg] += th * ad;
      }
    }
#pragma unroll
    for (int reg = 0; reg < 4; ++reg) {
#pragma unroll
      for (int off = 8; off; off >>= 1) {
        sp[reg] += __shfl_xor(sp[reg], off);
        dp[reg] += __shfl_xor(dp[reg], off);
      }
    }
    if ((lane & 15) == 0) {
#pragma unroll
      for (int reg = 0; reg < 4; ++reg) {
        int m = tile * 64 + wv * 16 + (lane >> 4) * 4 + reg;
        sT[((size_t)b * NN + m) * HH + h] = sp[reg] * LOG2E;
        dT[((size_t)b * NN + m) * HH + h] = dp[reg] * LOG2E;
      }
    }
    // epilogue 2: transpose into b_lds region
    unsigned short* tr = (unsigned short*)&b_lds[0][0][0];
#pragma unroll
    for (int nf = 0; nf < 4; ++nf) {
      int c = nf * 16 + (lane & 15);
#pragma unroll
      for (int reg = 0; reg < 4; ++reg) {
        int m = wv * 16 + (lane >> 4) * 4 + reg;
        tr[c * 76 + m] = f2b(acc[nf][reg]);
      }
    }
  }
  __syncthreads();
  if (g == 0) {
    const unsigned short* tr = (const unsigned short*)&b_lds[0][0][0];
    unsigned short* dst = hpT + (size_t)(b * HH + h) * 64 * NN + tile * 64;
#pragma unroll
    for (int q = 0; q < 2; ++q) {
      int e = q * 256 + tg;
      int o = e >> 3, j8 = (e & 7) * 8;
      u16x8 v;
#pragma unroll
      for (int z = 0; z < 8; ++z) v[z] = tr[o * 76 + j8 + z];
      *(u16x8*)&dst[(size_t)o * NN + j8] = v;
    }
  }
}

// ---------------- PV (MFMA, 512t, j-split halves, l via ones-MFMA) ----------
// MODE 0: aoutB bf16 [b,h,n,o].  MODE 1: hmidB bf16 [b,n,h*64+o] with ELU.
template <int MODE>
__global__ __launch_bounds__(512) void k_pv(
    const unsigned long long* __restrict__ bits, int r,
    const unsigned short* __restrict__ hpT,
    const float* __restrict__ sT, const float* __restrict__ dT,
    unsigned short* __restrict__ outB) {
  __shared__ unsigned short hp_lds[2][2][2][64 * 64];   // [group][dbuf][jt]
  __shared__ float d_lds[2][2][128];
  int i0 = blockIdx.x * 64, h = blockIdx.y, b = blockIdx.z;
  int t = threadIdx.x, lane = t & 63;
  int wid = t >> 6, g = wid >> 2, wv = wid & 3;
  int tg = t & 255;
  int jbase = g * 1024;
  int rowi = wv * 16 + (lane & 15);
  int kb = (lane >> 4) * 8;
  float sreg = sT[((size_t)b * NN + i0 + rowi) * HH + h];
  const unsigned long long* brow =
      bits + ((size_t)(b * NADJ + r) * NN + i0 + rowi) * (NN / 64) + g * 16;
  const unsigned short* hpTb = hpT + (size_t)(b * HH + h) * 64 * NN + jbase;
  const float* dTb = dT + ((size_t)b * NN + jbase) * HH + h;
  f32x4 acc[4] = {};
  f32x4 accl = {};
  const short ONE = (short)0x3F80;
  const s16x8 ones = {ONE, ONE, ONE, ONE, ONE, ONE, ONE, ONE};

  u16x8 ra[2], rb[2];
  float rd;
  tile_load(hpTb, NN, tg, ra[0], rb[0]);
  tile_load(hpTb + 64, NN, tg, ra[1], rb[1]);
  rd = (tg < 128) ? dTb[(size_t)tg * HH] : 0.f;
  tile_store(hp_lds[g][0][0], tg, ra[0], rb[0]);
  tile_store(hp_lds[g][0][1], tg, ra[1], rb[1]);
  if (tg < 128) d_lds[g][0][tg] = rd;
  tile_load(hpTb + 128, NN, tg, ra[0], rb[0]);
  tile_load(hpTb + 192, NN, tg, ra[1], rb[1]);
  rd = (tg < 128) ? dTb[(size_t)(128 + tg) * HH] : 0.f;
  unsigned long long bw0 = brow[0], bw1 = brow[1];
  __syncthreads();

  const int NT = 1024 / 128;   // 8 per group
  for (int it = 0; it < NT; ++it) {
    int buf = it & 1;
    if (it + 1 < NT) {
      tile_store(hp_lds[g][buf ^ 1][0], tg, ra[0], rb[0]);
      tile_store(hp_lds[g][buf ^ 1][1], tg, ra[1], rb[1]);
      if (tg < 128) d_lds[g][buf ^ 1][tg] = rd;
    }
    if (it + 2 < NT) {
      tile_load(hpTb + (it + 2) * 128, NN, tg, ra[0], rb[0]);
      tile_load(hpTb + (it + 2) * 128 + 64, NN, tg, ra[1], rb[1]);
      rd = (tg < 128) ? dTb[(size_t)((it + 2) * 128 + tg) * HH] : 0.f;
    }
    unsigned long long bwn0 = 0, bwn1 = 0;
    if (it + 1 < NT) { bwn0 = brow[2 * (it + 1)]; bwn1 = brow[2 * (it + 1) + 1]; }
#pragma unroll
    for (int jt = 0; jt < 2; ++jt) {
      unsigned long long bw = jt ? bw1 : bw0;
      unsigned int bsel[2];
      bsel[0] = (unsigned int)(bw >> kb);
      bsel[1] = (unsigned int)(bw >> (32 + kb));
      union { unsigned int u[4]; s16x8 v; } af[2];
#pragma unroll
      for (int kk = 0; kk < 2; ++kk) {
        float w8[8];
#pragma unroll
        for (int c = 0; c < 8; ++c) {
          float dv = d_lds[g][buf][jt * 64 + kk * 32 + kb + c];
          float x = sreg + dv;
          float xl = fmaxf(x, 0.2f * x);
          float e = __builtin_amdgcn_exp2f(xl);
          w8[c] = (bsel[kk] & (1u << c)) ? e : 0.f;
        }
#pragma unroll
        for (int p = 0; p < 4; ++p) {
          unsigned int pk;
          asm volatile("v_cvt_pk_bf16_f32 %0, %1, %2"
                       : "=v"(pk) : "v"(w8[2 * p]), "v"(w8[2 * p + 1]));
          af[kk].u[p] = pk;
        }
      }
#pragma unroll
      for (int kk = 0; kk < 2; ++kk) {
#pragma unroll
        for (int nf = 0; nf < 4; ++nf) {
          s16x8 bv = *tile_read_ptr(hp_lds[g][buf][jt], nf * 16 + (lane & 15),
                                    kk * 64 + (lane >> 4) * 16);
          acc[nf] = __builtin_amdgcn_mfma_f32_16x16x32_bf16(af[kk].v, bv, acc[nf], 0, 0, 0);
        }
        accl = __builtin_amdgcn_mfma_f32_16x16x32_bf16(af[kk].v, ones, accl, 0, 0, 0);
      }
    }
    bw0 = bwn0; bw1 = bwn1;
    __syncthreads();
  }
  // ---- combine: group 1 -> LDS, group 0 adds + writes ----------------------
  float* comb = (float*)&hp_lds[0][0][0][0];    // 16KB acc
  float* combl = comb + 4096;                   // 4KB l
  if (g == 1) {
    float* dst = comb + ((wv * 64 + lane) * 16);
#pragma unroll
    for (int nf = 0; nf < 4; ++nf)
#pragma unroll
      for (int reg = 0; reg < 4; ++reg) dst[nf * 4 + reg] = acc[nf][reg];
    float* dl = combl + (wv * 64 + lane) * 4;
#pragma unroll
    for (int reg = 0; reg < 4; ++reg) dl[reg] = accl[reg];
  }
  __syncthreads();
  if (g == 0) {
    const float* srcp = comb + ((wv * 64 + lane) * 16);
#pragma unroll
    for (int nf = 0; nf < 4; ++nf)
#pragma unroll
      for (int reg = 0; reg < 4; ++reg) acc[nf][reg] += srcp[nf * 4 + reg];
    const float* dl = combl + (wv * 64 + lane) * 4;
#pragma unroll
    for (int reg = 0; reg < 4; ++reg) accl[reg] += dl[reg];
    int col = lane & 15, r0g = (lane >> 4) * 4;
#pragma unroll
    for (int reg = 0; reg < 4; ++reg) {
      int m = wv * 16 + r0g + reg;
      float linv = 1.0f / accl[reg];
      if (MODE == 0) {
        size_t ob = (((size_t)b * HH + h) * NN + i0 + m) * 64 + col;
#pragma unroll
        for (int nf = 0; nf < 4; ++nf)
          outB[ob + nf * 16] = f2b(acc[nf][reg] * linv);
      } else {
        size_t ob = ((size_t)b * NN + i0 + m) * K1 + h * 64 + col;
#pragma unroll
        for (int nf = 0; nf < 4; ++nf) {
          float v = acc[nf][reg] * linv;
          v = v > 0.f ? v : (__builtin_amdgcn_exp2f(v * LOG2E) - 1.f);
          outB[ob + nf * 16] = f2b(v);
        }
      }
    }
  }
}

// ---------------- mean over heads → seq[b,n,r,:] (bf16 in) ------------------
__global__ __launch_bounds__(256) void k_mean(
    const unsigned short* __restrict__ in, float* __restrict__ seq, int r) {
  int idx = blockIdx.x * 256 + threadIdx.x;   // over BSZ*NN*8 (8 o's each)
  int o8 = (idx & 7) * 8;
  int n = (idx >> 3) & (NN - 1);
  int b = idx >> 14;
  float acc[8] = {};
#pragma unroll
  for (int h = 0; h < HH; ++h) {
    u16x8 v = *(const u16x8*)&in[(((size_t)b * HH + h) * NN + n) * 64 + o8];
#pragma unroll
    for (int z = 0; z < 8; ++z) acc[z] += b2f((unsigned short)v[z]);
  }
  float* dst = &seq[(((size_t)b * NN + n) * NADJ + r) * 64 + o8];
#pragma unroll
  for (int z = 0; z < 8; ++z) dst[z] = acc[z] * 0.125f;
}

// ---------------- final: fproj (feat@aw1) + fusion + log_softmax ------------
__global__ __launch_bounds__(256) void k_fuse(
    const unsigned short* __restrict__ featB, const float* __restrict__ aw1,
    const float* __restrict__ seq, const float* __restrict__ aw2,
    const float* __restrict__ am, float* __restrict__ outp) {
  __shared__ float w2[64][65];
  __shared__ float a1[NF][64];     // 48KB, direct copy of aw1
  __shared__ float amv[64];
  __shared__ unsigned short feat_l[4][NF];
  __shared__ float seq_lds[4][NADJ][64];
  int t = threadIdx.x;
#pragma unroll
  for (int q = 0; q < 16; ++q) {
    int e = t + 256 * q;
    w2[e >> 6][e & 63] = aw2[e];
  }
  float* a1f = &a1[0][0];
#pragma unroll
  for (int q = 0; q < 12; ++q) {
    int e4 = (t + 256 * q) * 4;
    *(float4*)&a1f[e4] = *(const float4*)&aw1[e4];
  }
  if (t < 64) amv[t] = am[t];
  int wid = t >> 6, lane = t & 63;
  int bn = blockIdx.x * 4 + wid;               // over BSZ*NN
  if (lane < 24)
    *(u16x8*)&feat_l[wid][lane * 8] = *(const u16x8*)&featB[(size_t)bn * NF + lane * 8];
  float s0 = seq[((size_t)bn * NADJ + 0) * 64 + lane];
  float s1 = seq[((size_t)bn * NADJ + 1) * 64 + lane];
  seq_lds[wid][0][lane] = s0;
  seq_lds[wid][1][lane] = s1;
  __syncthreads();
  // fproj: f = sum_k feat[bn][k] * aw1[k][lane]
  float f = 0.f;
#pragma unroll 4
  for (int kc = 0; kc < NF / 8; ++kc) {
    u16x8 fv = *(const u16x8*)&feat_l[wid][kc * 8];
#pragma unroll
    for (int z = 0; z < 8; ++z)
      f += b2f((unsigned short)fv[z]) * a1[kc * 8 + z][lane];
  }
  float q0 = f, q1 = f;
  for (int k = 0; k < 64; ++k) {
    float wv = w2[k][lane];
    q0 += seq_lds[wid][0][k] * wv;
    q1 += seq_lds[wid][1][k] * wv;
  }
  q0 = tanhf(q0); q1 = tanhf(q1);
  float sc0 = q0 * amv[lane], sc1 = q1 * amv[lane];
  for (int off = 32; off; off >>= 1) {
    sc0 += __shfl_xor(sc0, off);
    sc1 += __shfl_xor(sc1, off);
  }
  float mx = fmaxf(sc0, sc1);
  float e0 = __expf(sc0 - mx), e1 = __expf(sc1 - mx);
  float inv = 1.f / (e0 + e1);
  float fu = (e0 * inv) * s0 + (e1 * inv) * s1;
  float m = fu;
  for (int off = 32; off; off >>= 1) m = fmaxf(m, __shfl_xor(m, off));
  float ex = __expf(fu - m);
  float ssum = ex;
  for (int off = 32; off; off >>= 1) ssum += __shfl_xor(ssum, off);
  outp[(size_t)bn * 64 + lane] = fu - m - __logf(ssum);
}

extern "C" void kernel_launch(void* const* d_in, const int* in_sizes, int n_in,
                              void* d_out, int out_size, void* d_ws, size_t ws_size,
                              hipStream_t stream) {
  (void)in_sizes; (void)n_in; (void)out_size; (void)ws_size;
  const float* hg   = (const float*)d_in[0];
  const int*   vert = (const int*)d_in[1];
  const float* lemb = (const float*)d_in[2];
  const float* emb0 = (const float*)d_in[3];
  const float* emb1 = (const float*)d_in[4];
  const float* w_l0 = (const float*)d_in[5];
  const float* as0  = (const float*)d_in[6];
  const float* ad0  = (const float*)d_in[7];
  const float* w_l1 = (const float*)d_in[8];
  const float* as1  = (const float*)d_in[9];
  const float* ad1  = (const float*)d_in[10];
  const float* aw1  = (const float*)d_in[11];
  const float* aw2  = (const float*)d_in[12];
  const float* am   = (const float*)d_in[13];
  float* out = (float*)d_out;

  char* p = (char*)d_ws;
  unsigned short* hpT   = (unsigned short*)p;  p += (size_t)BSZ*HH*NN*64*2;   // 4MB
  unsigned short* aoutB = (unsigned short*)p;  p += (size_t)BSZ*HH*NN*64*2;   // 4MB
  unsigned short* featB = (unsigned short*)p;  p += (size_t)BSZ*NN*NF*2;      // 1.5MB
  unsigned short* hmidB = (unsigned short*)p;  p += (size_t)BSZ*NN*K1*2;      // 4MB
  unsigned short* wT0   = (unsigned short*)p;  p += (size_t)NADJ*HH*64*NF*2;
  unsigned short* wT1   = (unsigned short*)p;  p += (size_t)NADJ*HH*64*K1*2;
  float* sT             = (float*)p;           p += (size_t)BSZ*NN*HH*4;
  float* dT             = (float*)p;           p += (size_t)BSZ*NN*HH*4;
  unsigned long long* bits = (unsigned long long*)p; p += (size_t)BSZ*NADJ*NN*(NN/64)*8;
  float* seq            = (float*)p;           p += (size_t)BSZ*NN*NADJ*64*4;

  // one-time prep
  k_build_feat<<<(BSZ*NN*NF)/256, 256, 0, stream>>>(vert, lemb, emb0, emb1, featB);
  k_bits<<<(size_t)BSZ*NADJ*NN*NN/256, 256, 0, stream>>>(hg, bits);
  k_tcast<<<dim3(NF/64, NADJ*HH), 256, 0, stream>>>(w_l0, wT0, NF);
  k_tcast<<<dim3(K1/64, NADJ*HH), 256, 0, stream>>>(w_l1, wT1, K1);

  for (int r = 0; r < NADJ; ++r) {
    // layer 0
    k_gemm_fused<NF><<<dim3(NN/64, HH, BSZ), 256, 0, stream>>>(
        featB, wT0 + (size_t)r*HH*64*NF, as0 + r*HH*64, ad0 + r*HH*64, hpT, sT, dT);
    k_pv<1><<<dim3(NN/64, HH, BSZ), 512, 0, stream>>>(bits, r, hpT, sT, dT, hmidB);
    // layer 1
    k_gemm_fused_ks<<<dim3(NN/64, HH, BSZ), 512, 0, stream>>>(
        hmidB, wT1 + (size_t)r*HH*64*K1, as1 + r*HH*64, ad1 + r*HH*64, hpT, sT, dT);
    k_pv<0><<<dim3(NN/64, HH, BSZ), 512, 0, stream>>>(bits, r, hpT, sT, dT, aoutB);
    k_mean<<<(BSZ*NN*8)/256, 256, 0, stream>>>(aoutB, seq, r);
  }
  k_fuse<<<BSZ*NN/4, 256, 0, stream>>>(featB, aw1, seq, aw2, am, out);
}